// Round 8
// baseline (4544.277 us; speedup 1.0000x reference)
//
#include <hip/hip_runtime.h>
#include <hip/hip_bf16.h>

#define TT 128
#define BB 256
#define OBSD 1024
#define FEATD 512
#define NA 15
#define DD 528
#define GG 2112   // 4*DD
#define KK 1056   // 2*DD
#define SCL 4096.f
#define INV_SCL (1.f/4096.f)

using half8 = __attribute__((ext_vector_type(8))) _Float16;
using f32x4 = __attribute__((ext_vector_type(4))) float;

__device__ __forceinline__ void split1(float v, _Float16& h, _Float16& l){
  h = (_Float16)v;
  l = (_Float16)((v - (float)h) * SCL);
}
__device__ __forceinline__ float sigf(float x){ return 1.f/(1.f + expf(-x)); }
__device__ __forceinline__ int swz(int r){ return (r ^ (r >> 2)) & 3; }

// global->LDS direct staging. aux=17 (SC0|SC1): device coherence point (safe vs
// stale per-XCD L2; validated r5-r7). aux=0: normal cached.
#define GLOAD_LDS(g, s, aux) \
  __builtin_amdgcn_global_load_lds((const __attribute__((address_space(1))) void*)(g), \
                                   (__attribute__((address_space(3))) void*)(s), 16, 0, (aux))

// ---------------- prep kernels ----------------

// W pre-swizzled to per-lane MFMA fragment order:
// flat d = ((js*2+p)*33 + s)*2048 + plane*1024 + gi*512 + lane*8 + h
// lane: wrow-local = lane&15, kchunk = lane>>4 ; wrow = (2p+gi)*DD + js*16 + (lane&15)
__global__ void k_prep_wsw(const float* __restrict__ wih, const float* __restrict__ whh,
                           const float* __restrict__ bih, const float* __restrict__ bhh,
                           _Float16* __restrict__ Wsw, float* __restrict__ bias){
  const int n = 2*GG*KK;
  for (int d = blockIdx.x*blockDim.x + threadIdx.x; d < n; d += gridDim.x*blockDim.x){
    int h     = d & 7;
    int lane  = (d >> 3) & 63;
    int gi    = (d >> 9) & 1;
    int plane = (d >> 10) & 1;
    int rest  = d >> 11;          // (js*2+p)*33 + s
    int s  = rest % 33;
    int jp = rest / 33;
    int p = jp & 1, js = jp >> 1;
    int g = 2*p + gi;
    int wrow = g*DD + js*16 + (lane & 15);
    int col  = s*32 + (lane >> 4)*8 + h;
    float v = (col < DD) ? wih[wrow*DD + col] : whh[wrow*DD + (col - DD)];
    _Float16 hh, ll; split1(v, hh, ll);
    Wsw[d] = plane ? ll : hh;
    if (d < GG) bias[d] = bih[d] + bhh[d];
  }
}

__global__ void k_conv_encw(const float* __restrict__ src,
                            _Float16* __restrict__ dh, _Float16* __restrict__ dl){
  const int n = FEATD*OBSD;
  for (int i = blockIdx.x*blockDim.x + threadIdx.x; i < n; i += gridDim.x*blockDim.x)
    split1(src[i], dh[i], dl[i]);
}

__global__ void k_fill_extra(const float* __restrict__ reward, const int* __restrict__ act,
                             _Float16* __restrict__ xh, _Float16* __restrict__ xl){
  int row = blockIdx.x*blockDim.x + threadIdx.x;
  if (row >= TT*BB) return;
  float r = fminf(1.f, fmaxf(-1.f, reward[row]));
  size_t base = (size_t)row*DD + FEATD;
  _Float16 hh, hl;
  split1(r, hh, hl);
  xh[base] = hh; xl[base] = hl;
  int a = act[row];
  #pragma unroll
  for (int i = 0; i < NA; ++i){
    xh[base+1+i] = (i == a) ? (_Float16)1.0f : (_Float16)0.0f;
    xl[base+1+i] = (_Float16)0.0f;
  }
}

// ---------------- encoder GEMM -> x planes cols 0..511 ----------------
__launch_bounds__(256)
__global__ void k_encoder(const float* __restrict__ obs, const _Float16* __restrict__ ench,
                          const _Float16* __restrict__ encl,
                          const float* __restrict__ encb,
                          _Float16* __restrict__ xh, _Float16* __restrict__ xl){
  __shared__ _Float16 Ah[128][40], Al[128][40], Bh[128][40], Bl[128][40];
  const int mt = blockIdx.x, nt = blockIdx.y;
  const int tid = threadIdx.x, w = tid >> 6, l = tid & 63;
  const int wm = (w >> 1)*64, wn = (w & 1)*64;
  const int m0 = mt*128, n0 = nt*128;
  f32x4 acc1[4][4], acc2[4][4];
  #pragma unroll
  for (int m = 0; m < 4; ++m)
    #pragma unroll
    for (int n = 0; n < 4; ++n)
      #pragma unroll
      for (int q = 0; q < 4; ++q){ acc1[m][n][q]=0.f; acc2[m][n][q]=0.f; }

  for (int k0 = 0; k0 < OBSD; k0 += 32){
    {
      int row = tid >> 1, c0 = (tid & 1)*16;
      const float* src = obs + (size_t)(m0+row)*OBSD + k0 + c0;
      #pragma unroll
      for (int cc = 0; cc < 16; ++cc){
        float v = src[cc];
        split1(v, Ah[row][c0+cc], Al[row][c0+cc]);
      }
      const _Float16* bh = ench + (size_t)(n0+row)*OBSD + k0 + c0;
      const _Float16* bl = encl + (size_t)(n0+row)*OBSD + k0 + c0;
      *(half8*)&Bh[row][c0]   = *(const half8*)(bh);
      *(half8*)&Bh[row][c0+8] = *(const half8*)(bh+8);
      *(half8*)&Bl[row][c0]   = *(const half8*)(bl);
      *(half8*)&Bl[row][c0+8] = *(const half8*)(bl+8);
    }
    __syncthreads();
    half8 ah[4], al[4], bh[4], bl[4];
    #pragma unroll
    for (int m = 0; m < 4; ++m){
      ah[m] = *(const half8*)&Ah[wm + m*16 + (l & 15)][(l >> 4)*8];
      al[m] = *(const half8*)&Al[wm + m*16 + (l & 15)][(l >> 4)*8];
    }
    #pragma unroll
    for (int n = 0; n < 4; ++n){
      bh[n] = *(const half8*)&Bh[wn + n*16 + (l & 15)][(l >> 4)*8];
      bl[n] = *(const half8*)&Bl[wn + n*16 + (l & 15)][(l >> 4)*8];
    }
    #pragma unroll
    for (int m = 0; m < 4; ++m)
      #pragma unroll
      for (int n = 0; n < 4; ++n){
        acc1[m][n] = __builtin_amdgcn_mfma_f32_16x16x32_f16(ah[m], bh[n], acc1[m][n], 0, 0, 0);
        acc2[m][n] = __builtin_amdgcn_mfma_f32_16x16x32_f16(ah[m], bl[n], acc2[m][n], 0, 0, 0);
        acc2[m][n] = __builtin_amdgcn_mfma_f32_16x16x32_f16(al[m], bh[n], acc2[m][n], 0, 0, 0);
      }
    __syncthreads();
  }
  #pragma unroll
  for (int m = 0; m < 4; ++m)
    #pragma unroll
    for (int n = 0; n < 4; ++n)
      #pragma unroll
      for (int q = 0; q < 4; ++q){
        int row = m0 + wm + m*16 + (l >> 4)*4 + q;
        int col = n0 + wn + n*16 + (l & 15);
        float v = acc1[m][n][q] + acc2[m][n][q]*INV_SCL + encb[col];
        v = fmaxf(v, 0.f);
        _Float16 hh, hl;
        split1(v, hh, hl);
        size_t off = (size_t)row*DD + col;
        xh[off] = hh; xl[off] = hl;
      }
}

// ---------------- persistent recurrence kernel ----------------
// 264 blocks launched, 132 active (4 mt x 33 js), 512 threads (8 waves), 1 blk/CU.
// W: pre-swizzled fragment layout, plain cached dwordx4 -> registers (no LDS).
// A: staged in 8-slab 64KB chunks, ring-2 LDS, depth-1 top-issue (transfer overlaps
// the 8-slab compute), 6 barriers/phase. Flag-gated chunks issued post-compute.
// Wave wv: M-tile (wv&3) x gate-pair (wv>>2); c-state in regs; gbuf epilogue.
__launch_bounds__(512)
__global__ void k_recur(_Float16* xh, _Float16* xl,
                        _Float16* h1h0, _Float16* h1l0,
                        _Float16* h1h1, _Float16* h1l1,
                        const _Float16* __restrict__ Wsw0, const _Float16* __restrict__ Wsw1,
                        const float* __restrict__ bias0, const float* __restrict__ bias1,
                        const int* __restrict__ term, int* flags,
                        const _Float16* __restrict__ zp){
  __shared__ _Float16 S[2][8][2][64][32];   // [ring][slab][plane][row][col] = 128KB
  __shared__ float gbuf[4][64][16];         // 16KB

  const int tid = threadIdx.x, wv = tid >> 6, l = tid & 63;
  const int b = blockIdx.x;
  const int xcd = b & 7, slot_id = b >> 3;
  int mt, js;
  if (slot_id < 16){ js = xcd + 8*(slot_id >> 2); mt = slot_id & 3; }
  else if (slot_id == 16 && (xcd & 1)){ js = 32; mt = xcd >> 1; }
  else return;
  const int m0 = mt*64, j0 = js*16;

  // staging role: thread stages 16B of one (plane,row,chunk) per slab
  const int st_plane = tid >> 8;                 // 0:hi 1:lo
  const int st_row   = (tid & 255) >> 2;         // 0..63
  const int st_gblk  = (tid & 3) ^ swz(st_row);  // pre-swizzled source chunk
  const size_t st_aoff = (size_t)(m0 + st_row)*DD;
  _Float16* const st_base = &S[0][0][st_plane][(wv & 3)*16][0];

  // compute role
  const int p = wv >> 2, g0 = 2*p, mrow = (wv & 3)*16;
  const int fr = mrow + (l & 15);
  const int fb = ((l >> 4) ^ swz(fr))*8;
  const int wbase_idx = (js*2 + p)*33;

  // epilogue role
  const int er0 = tid >> 4, ec = tid & 15, er1 = er0 + 32;
  const int jc = j0 + ec;

  float c1r[2] = {0.f,0.f}, c2r[2] = {0.f,0.f};
  f32x4 accm[2], accc[2];

  auto flag_wait = [&](int idx){
    if (tid == 0){
      while (__hip_atomic_load(&flags[idx], __ATOMIC_RELAXED, __HIP_MEMORY_SCOPE_AGENT) < 33)
        __builtin_amdgcn_s_sleep(2);
    }
    __builtin_amdgcn_s_barrier();
    __builtin_amdgcn_sched_barrier(0);
  };
  auto flag_post = [&](int idx){
    asm volatile("s_waitcnt vmcnt(0)" ::: "memory");
    __builtin_amdgcn_s_barrier();
    if (tid == 0)
      __hip_atomic_fetch_add(&flags[idx], 1, __ATOMIC_RELAXED, __HIP_MEMORY_SCOPE_AGENT);
  };

  auto epilogue = [&](const float* bias, float* cr, _Float16* dh, _Float16* dl,
                      const int* term_t){
    #pragma unroll
    for (int gi = 0; gi < 2; ++gi)
      #pragma unroll
      for (int q = 0; q < 4; ++q)
        gbuf[g0 + gi][mrow + (l >> 4)*4 + q][l & 15] = accm[gi][q] + accc[gi][q]*INV_SCL;
    __syncthreads();
    #pragma unroll
    for (int pp = 0; pp < 2; ++pp){
      const int er = pp ? er1 : er0;
      const int row = m0 + er;
      float iv = gbuf[0][er][ec] + bias[jc];
      float fv = gbuf[1][er][ec] + bias[DD + jc];
      float gv = gbuf[2][er][ec] + bias[2*DD + jc];
      float ov = gbuf[3][er][ec] + bias[3*DD + jc];
      float cp = (term_t[row] == 0) ? cr[pp] : 0.f;
      float cn = sigf(fv)*cp + sigf(iv)*tanhf(gv);
      float hn = sigf(ov)*tanhf(cn);
      cr[pp] = cn;
      _Float16 hh, hl;
      split1(hn, hh, hl);
      size_t off = (size_t)row*DD + jc;
      __hip_atomic_store((unsigned short*)(dh + off), __builtin_bit_cast(unsigned short, hh),
                         __ATOMIC_RELAXED, __HIP_MEMORY_SCOPE_AGENT);
      __hip_atomic_store((unsigned short*)(dl + off), __builtin_bit_cast(unsigned short, hl),
                         __ATOMIC_RELAXED, __HIP_MEMORY_SCOPE_AGENT);
    }
    __syncthreads();
  };

  auto run_phase = [&](bool isL1,
                       const _Float16* p1h, const _Float16* p1l,
                       const _Float16* p2h, const _Float16* p2l, bool nd,
                       const _Float16* __restrict__ WswL,
                       int fC0, int fC2){
    #pragma unroll
    for (int g = 0; g < 2; ++g)
      #pragma unroll
      for (int q = 0; q < 4; ++q){ accm[g][q]=0.f; accc[g][q]=0.f; }

    const _Float16* P1 = st_plane ? p1l : p1h;
    const _Float16* P2 = st_plane ? p2l : p2h;

    auto slabId = [&](int ci, int j){
      return isL1 ? (ci < 2 ? 17 + ci*8 + j : (ci < 4 ? (ci-2)*8 + j : 16))
                  : (ci < 4 ? ci*8 + j : 32);
    };
    auto issue_chunk = [&](int ci){
      const int ring = ci & 1;
      const int ns = (ci == 4) ? 1 : 8;
      for (int j = 0; j < ns; ++j){
        const int s = slabId(ci, j);
        const int col = s*32 + st_gblk*8;
        const _Float16* src;
        if (col < DD) src = P1 + st_aoff + col;
        else          src = nd ? (P2 + st_aoff + (col - DD)) : zp;
        _Float16* dst = st_base + ring*32768 + j*4096;
        if (isL1 || s >= 16) GLOAD_LDS(src, dst, 17);
        else                 GLOAD_LDS(src, dst, 0);
      }
    };
    auto compute_slab = [&](int ring, int j, int s){
      const _Float16* wp = WswL + (size_t)(wbase_idx + s)*2048 + (size_t)l*8;
      half8 bh0 = *(const half8*)(wp);
      half8 bh1 = *(const half8*)(wp + 512);
      half8 bl0 = *(const half8*)(wp + 1024);
      half8 bl1 = *(const half8*)(wp + 1536);
      half8 fah = *(const half8*)&S[ring][j][0][fr][fb];
      half8 fal = *(const half8*)&S[ring][j][1][fr][fb];
      accm[0] = __builtin_amdgcn_mfma_f32_16x16x32_f16(fah, bh0, accm[0], 0, 0, 0);
      accc[0] = __builtin_amdgcn_mfma_f32_16x16x32_f16(fah, bl0, accc[0], 0, 0, 0);
      accc[0] = __builtin_amdgcn_mfma_f32_16x16x32_f16(fal, bh0, accc[0], 0, 0, 0);
      accm[1] = __builtin_amdgcn_mfma_f32_16x16x32_f16(fah, bh1, accm[1], 0, 0, 0);
      accc[1] = __builtin_amdgcn_mfma_f32_16x16x32_f16(fah, bl1, accc[1], 0, 0, 0);
      accc[1] = __builtin_amdgcn_mfma_f32_16x16x32_f16(fal, bh1, accc[1], 0, 0, 0);
    };

    // prologue: chunk0 (flag-gated for L1's h2-part)
    if (fC0 >= 0) flag_wait(fC0);
    issue_chunk(0);
    asm volatile("s_waitcnt vmcnt(0)" ::: "memory");
    __builtin_amdgcn_s_barrier();
    __builtin_amdgcn_sched_barrier(0);

    #pragma unroll
    for (int ci = 0; ci < 5; ++ci){
      const bool nextFlagged = (ci + 1 == 2) && (fC2 >= 0);
      if (ci + 1 <= 4 && !nextFlagged) issue_chunk(ci + 1);   // top-issue: overlaps compute
      const int ring = ci & 1;
      const int ns = (ci == 4) ? 1 : 8;
      #pragma unroll
      for (int j = 0; j < ns; ++j) compute_slab(ring, j, slabId(ci, j));
      if (ci + 1 <= 4 && nextFlagged){ flag_wait(fC2); issue_chunk(ci + 1); }
      asm volatile("s_waitcnt vmcnt(0)" ::: "memory");
      __builtin_amdgcn_s_barrier();
      __builtin_amdgcn_sched_barrier(0);
    }
  };

  _Float16* h1h[2] = {h1h0, h1h1};
  _Float16* h1l[2] = {h1l0, h1l1};

  #pragma unroll 1
  for (int t = 0; t < TT; ++t){
    const int* term_t = term + t*BB;
    const bool ndrow = (t > 0) && (term_t[m0 + st_row] == 0);
    _Float16* xth = xh + (size_t)t*BB*DD;
    _Float16* xtl = xl + (size_t)t*BB*DD;
    const _Float16* xph = xh + (size_t)(t > 0 ? t-1 : 0)*BB*DD;
    const _Float16* xpl = xl + (size_t)(t > 0 ? t-1 : 0)*BB*DD;

    // ===== layer 0: gates = [x(t) | h1(t-1)*nd] @ W0^T =====
    run_phase(false, xth, xtl, h1h[(t+1)&1], h1l[(t+1)&1], ndrow, Wsw0,
              -1, (t >= 1) ? (t-1)*8 + mt : -1);
    if (t >= 2) flag_wait((t-2)*8 + 4 + mt);           // WAR on h1 buffer t&1
    epilogue(bias0, c1r, h1h[t&1], h1l[t&1], term_t);
    flag_post(t*8 + mt);

    // ===== layer 1: gates = [h1(t) | h2(t-1)*nd] @ W1^T ; h2(t-1)=x[t-1] alias =====
    run_phase(true, h1h[t&1], h1l[t&1], xph, xpl, ndrow, Wsw1,
              (t >= 1) ? (t-1)*8 + 4 + mt : -1, t*8 + mt);
    epilogue(bias1, c2r, xth, xtl, term_t);            // h2(t) overwrites x[t]
    flag_post(t*8 + 4 + mt);
  }
}

// ---------------- heads: logits/baseline/action ----------------
__launch_bounds__(256)
__global__ void k_heads(const _Float16* __restrict__ oh, const _Float16* __restrict__ ol,
                        const float* __restrict__ polw, const float* __restrict__ basew,
                        const float* __restrict__ polb, const float* __restrict__ baseb,
                        float* __restrict__ dout){
  __shared__ _Float16 Ah[128][40], Al[128][40];
  __shared__ _Float16 Bh[16][552], Bl[16][552];
  const int bid = blockIdx.x;
  const int tid = threadIdx.x, w = tid >> 6, l = tid & 63;
  const int m0 = bid*128;

  for (int i = tid; i < 16*544; i += 256){
    int r = i / 544, c = i % 544;
    float v = 0.f;
    if (c < DD) v = (r < NA) ? polw[r*DD + c] : basew[c];
    split1(v, Bh[r][c], Bl[r][c]);
  }
  __syncthreads();

  f32x4 acc1[2], acc2[2];
  #pragma unroll
  for (int m = 0; m < 2; ++m)
    #pragma unroll
    for (int q = 0; q < 4; ++q){ acc1[m][q]=0.f; acc2[m][q]=0.f; }

  for (int it = 0; it < 17; ++it){
    const int k0 = it*32;
    {
      int row = tid >> 1, c0 = (tid & 1)*16;
      size_t off = (size_t)(m0+row)*DD + k0 + c0;   // overreads pad; B=0 there
      *(half8*)&Ah[row][c0]   = *(const half8*)(oh + off);
      *(half8*)&Ah[row][c0+8] = *(const half8*)(oh + off + 8);
      *(half8*)&Al[row][c0]   = *(const half8*)(ol + off);
      *(half8*)&Al[row][c0+8] = *(const half8*)(ol + off + 8);
    }
    __syncthreads();
    half8 fbh = *(const half8*)&Bh[l & 15][k0 + (l >> 4)*8];
    half8 fbl = *(const half8*)&Bl[l & 15][k0 + (l >> 4)*8];
    #pragma unroll
    for (int m = 0; m < 2; ++m){
      half8 fah = *(const half8*)&Ah[w*32 + m*16 + (l & 15)][(l >> 4)*8];
      half8 fal = *(const half8*)&Al[w*32 + m*16 + (l & 15)][(l >> 4)*8];
      acc1[m] = __builtin_amdgcn_mfma_f32_16x16x32_f16(fah, fbh, acc1[m], 0, 0, 0);
      acc2[m] = __builtin_amdgcn_mfma_f32_16x16x32_f16(fah, fbl, acc2[m], 0, 0, 0);
      acc2[m] = __builtin_amdgcn_mfma_f32_16x16x32_f16(fal, fbh, acc2[m], 0, 0, 0);
    }
    __syncthreads();
  }

  const int a = l & 15;
  const size_t base_off = (size_t)TT*BB*NA;
  const size_t act_off  = base_off + (size_t)TT*BB;
  #pragma unroll
  for (int m = 0; m < 2; ++m)
    #pragma unroll
    for (int q = 0; q < 4; ++q){
      int r = m0 + w*32 + m*16 + (l >> 4)*4 + q;
      float v = acc1[m][q] + acc2[m][q]*INV_SCL + ((a < NA) ? polb[a] : baseb[0]);
      float key = (a < NA) ? v : -3.4e38f;
      int ki = a;
      #pragma unroll
      for (int s = 1; s < 16; s <<= 1){
        float ov = __shfl_xor(key, s, 64);
        int   oi = __shfl_xor(ki,  s, 64);
        if (ov > key || (ov == key && oi < ki)){ key = ov; ki = oi; }
      }
      if (a < NA) dout[(size_t)r*NA + a] = v;
      if (a == NA) dout[base_off + r] = v;
      if (a == 0)  dout[act_off + r] = (float)ki;
    }
}

// ---------------- launch ----------------
extern "C" void kernel_launch(void* const* d_in, const int* in_sizes, int n_in,
                              void* d_out, int out_size, void* d_ws, size_t ws_size,
                              hipStream_t stream){
  const float* obs        = (const float*)d_in[0];
  const int*   last_act   = (const int*)  d_in[1];
  const float* reward     = (const float*)d_in[2];
  const int*   terminated = (const int*)  d_in[3];
  const float* enc_w      = (const float*)d_in[4];
  const float* enc_b      = (const float*)d_in[5];
  const float* w_ih0      = (const float*)d_in[6];
  const float* w_hh0      = (const float*)d_in[7];
  const float* b_ih0      = (const float*)d_in[8];
  const float* b_hh0      = (const float*)d_in[9];
  const float* w_ih1      = (const float*)d_in[10];
  const float* w_hh1      = (const float*)d_in[11];
  const float* b_ih1      = (const float*)d_in[12];
  const float* b_hh1      = (const float*)d_in[13];
  const float* pol_w      = (const float*)d_in[14];
  const float* pol_b      = (const float*)d_in[15];
  const float* base_w     = (const float*)d_in[16];
  const float* base_b     = (const float*)d_in[17];

  char* ws = (char*)d_ws;
  size_t o = 0;
  auto alloc = [&](size_t bytes){ size_t r = o; o += (bytes + 255) & ~(size_t)255; return r; };

  _Float16* Wsw0  = (_Float16*)(ws + alloc((size_t)GG*KK*4));   // hi+lo interleaved
  _Float16* Wsw1  = (_Float16*)(ws + alloc((size_t)GG*KK*4));
  float* bias0    = (float*)(ws + alloc((size_t)GG*4));
  float* bias1    = (float*)(ws + alloc((size_t)GG*4));
  _Float16* ench  = (_Float16*)(ws + alloc((size_t)FEATD*OBSD*2));
  _Float16* encl  = (_Float16*)(ws + alloc((size_t)FEATD*OBSD*2));
  _Float16* xh    = (_Float16*)(ws + alloc((size_t)TT*BB*DD*2 + 4096));  // x / h2-out hi
  _Float16* xl    = (_Float16*)(ws + alloc((size_t)TT*BB*DD*2 + 4096));  // lo plane
  _Float16* h1h0  = (_Float16*)(ws + alloc((size_t)BB*DD*2));
  _Float16* h1l0  = (_Float16*)(ws + alloc((size_t)BB*DD*2));
  _Float16* h1h1  = (_Float16*)(ws + alloc((size_t)BB*DD*2));
  _Float16* h1l1  = (_Float16*)(ws + alloc((size_t)BB*DD*2));
  int*   flags    = (int*)(ws + alloc((size_t)TT*8*4 + 256));   // + zero page
  _Float16* zp    = (_Float16*)((char*)flags + TT*8*4);

  hipMemsetAsync(flags, 0, (size_t)TT*8*4 + 256, stream);

  k_prep_wsw<<<4096, 256, 0, stream>>>(w_ih0, w_hh0, b_ih0, b_hh0, Wsw0, bias0);
  k_prep_wsw<<<4096, 256, 0, stream>>>(w_ih1, w_hh1, b_ih1, b_hh1, Wsw1, bias1);
  k_conv_encw<<<2048, 256, 0, stream>>>(enc_w, ench, encl);
  k_fill_extra<<<TT*BB/256, 256, 0, stream>>>(reward, last_act, xh, xl);

  dim3 eg(TT*BB/128, FEATD/128);
  k_encoder<<<eg, 256, 0, stream>>>(obs, ench, encl, enc_b, xh, xl);

  k_recur<<<264, 512, 0, stream>>>(xh, xl, h1h0, h1l0, h1h1, h1l1,
                                   Wsw0, Wsw1, bias0, bias1,
                                   terminated, flags, zp);

  k_heads<<<TT*BB/128, 256, 0, stream>>>(xh, xl, pol_w, base_w, pol_b, base_b, (float*)d_out);
}

// Round 9
// 3984.549 us; speedup vs baseline: 1.1405x; 1.1405x over previous
//
#include <hip/hip_runtime.h>
#include <hip/hip_bf16.h>

#define TT 128
#define BB 256
#define OBSD 1024
#define FEATD 512
#define NA 15
#define DD 528
#define GG 2112   // 4*DD
#define KK 1056   // 2*DD
#define SCL 4096.f
#define INV_SCL (1.f/4096.f)

using half8 = __attribute__((ext_vector_type(8))) _Float16;
using f32x4 = __attribute__((ext_vector_type(4))) float;

__device__ __forceinline__ void split1(float v, _Float16& h, _Float16& l){
  h = (_Float16)v;
  l = (_Float16)((v - (float)h) * SCL);
}
__device__ __forceinline__ float sigf(float x){ return 1.f/(1.f + expf(-x)); }

// global->LDS direct staging. aux=17 (SC0|SC1): device coherence point (safe vs
// stale per-XCD L2; validated r5-r8). aux=0: normal cached.
#define GLOAD_LDS(g, s, aux) \
  __builtin_amdgcn_global_load_lds((const __attribute__((address_space(1))) void*)(g), \
                                   (__attribute__((address_space(3))) void*)(s), 16, 0, (aux))

// ---------------- prep kernels ----------------

// W pre-swizzled to per-lane MFMA fragment order:
// flat d = ((js*2+p)*33 + s)*2048 + plane*1024 + gi*512 + lane*8 + h
__global__ void k_prep_wsw(const float* __restrict__ wih, const float* __restrict__ whh,
                           const float* __restrict__ bih, const float* __restrict__ bhh,
                           _Float16* __restrict__ Wsw, float* __restrict__ bias){
  const int n = 2*GG*KK;
  for (int d = blockIdx.x*blockDim.x + threadIdx.x; d < n; d += gridDim.x*blockDim.x){
    int h     = d & 7;
    int lane  = (d >> 3) & 63;
    int gi    = (d >> 9) & 1;
    int plane = (d >> 10) & 1;
    int rest  = d >> 11;          // (js*2+p)*33 + s
    int s  = rest % 33;
    int jp = rest / 33;
    int p = jp & 1, js = jp >> 1;
    int g = 2*p + gi;
    int wrow = g*DD + js*16 + (lane & 15);
    int col  = s*32 + (lane >> 4)*8 + h;
    float v = (col < DD) ? wih[wrow*DD + col] : whh[wrow*DD + (col - DD)];
    _Float16 hh, ll; split1(v, hh, ll);
    Wsw[d] = plane ? ll : hh;
    if (d < GG) bias[d] = bih[d] + bhh[d];
  }
}

__global__ void k_conv_encw(const float* __restrict__ src,
                            _Float16* __restrict__ dh, _Float16* __restrict__ dl){
  const int n = FEATD*OBSD;
  for (int i = blockIdx.x*blockDim.x + threadIdx.x; i < n; i += gridDim.x*blockDim.x)
    split1(src[i], dh[i], dl[i]);
}

__global__ void k_fill_extra(const float* __restrict__ reward, const int* __restrict__ act,
                             _Float16* __restrict__ xh, _Float16* __restrict__ xl){
  int row = blockIdx.x*blockDim.x + threadIdx.x;
  if (row >= TT*BB) return;
  float r = fminf(1.f, fmaxf(-1.f, reward[row]));
  size_t base = (size_t)row*DD + FEATD;
  _Float16 hh, hl;
  split1(r, hh, hl);
  xh[base] = hh; xl[base] = hl;
  int a = act[row];
  #pragma unroll
  for (int i = 0; i < NA; ++i){
    xh[base+1+i] = (i == a) ? (_Float16)1.0f : (_Float16)0.0f;
    xl[base+1+i] = (_Float16)0.0f;
  }
}

// ---------------- encoder GEMM -> x planes cols 0..511 ----------------
__launch_bounds__(256)
__global__ void k_encoder(const float* __restrict__ obs, const _Float16* __restrict__ ench,
                          const _Float16* __restrict__ encl,
                          const float* __restrict__ encb,
                          _Float16* __restrict__ xh, _Float16* __restrict__ xl){
  __shared__ _Float16 Ah[128][40], Al[128][40], Bh[128][40], Bl[128][40];
  const int mt = blockIdx.x, nt = blockIdx.y;
  const int tid = threadIdx.x, w = tid >> 6, l = tid & 63;
  const int wm = (w >> 1)*64, wn = (w & 1)*64;
  const int m0 = mt*128, n0 = nt*128;
  f32x4 acc1[4][4], acc2[4][4];
  #pragma unroll
  for (int m = 0; m < 4; ++m)
    #pragma unroll
    for (int n = 0; n < 4; ++n)
      #pragma unroll
      for (int q = 0; q < 4; ++q){ acc1[m][n][q]=0.f; acc2[m][n][q]=0.f; }

  for (int k0 = 0; k0 < OBSD; k0 += 32){
    {
      int row = tid >> 1, c0 = (tid & 1)*16;
      const float* src = obs + (size_t)(m0+row)*OBSD + k0 + c0;
      #pragma unroll
      for (int cc = 0; cc < 16; ++cc){
        float v = src[cc];
        split1(v, Ah[row][c0+cc], Al[row][c0+cc]);
      }
      const _Float16* bh = ench + (size_t)(n0+row)*OBSD + k0 + c0;
      const _Float16* bl = encl + (size_t)(n0+row)*OBSD + k0 + c0;
      *(half8*)&Bh[row][c0]   = *(const half8*)(bh);
      *(half8*)&Bh[row][c0+8] = *(const half8*)(bh+8);
      *(half8*)&Bl[row][c0]   = *(const half8*)(bl);
      *(half8*)&Bl[row][c0+8] = *(const half8*)(bl+8);
    }
    __syncthreads();
    half8 ah[4], al[4], bh[4], bl[4];
    #pragma unroll
    for (int m = 0; m < 4; ++m){
      ah[m] = *(const half8*)&Ah[wm + m*16 + (l & 15)][(l >> 4)*8];
      al[m] = *(const half8*)&Al[wm + m*16 + (l & 15)][(l >> 4)*8];
    }
    #pragma unroll
    for (int n = 0; n < 4; ++n){
      bh[n] = *(const half8*)&Bh[wn + n*16 + (l & 15)][(l >> 4)*8];
      bl[n] = *(const half8*)&Bl[wn + n*16 + (l & 15)][(l >> 4)*8];
    }
    #pragma unroll
    for (int m = 0; m < 4; ++m)
      #pragma unroll
      for (int n = 0; n < 4; ++n){
        acc1[m][n] = __builtin_amdgcn_mfma_f32_16x16x32_f16(ah[m], bh[n], acc1[m][n], 0, 0, 0);
        acc2[m][n] = __builtin_amdgcn_mfma_f32_16x16x32_f16(ah[m], bl[n], acc2[m][n], 0, 0, 0);
        acc2[m][n] = __builtin_amdgcn_mfma_f32_16x16x32_f16(al[m], bh[n], acc2[m][n], 0, 0, 0);
      }
    __syncthreads();
  }
  #pragma unroll
  for (int m = 0; m < 4; ++m)
    #pragma unroll
    for (int n = 0; n < 4; ++n)
      #pragma unroll
      for (int q = 0; q < 4; ++q){
        int row = m0 + wm + m*16 + (l >> 4)*4 + q;
        int col = n0 + wn + n*16 + (l & 15);
        float v = acc1[m][n][q] + acc2[m][n][q]*INV_SCL + encb[col];
        v = fmaxf(v, 0.f);
        _Float16 hh, hl;
        split1(v, hh, hl);
        size_t off = (size_t)row*DD + col;
        xh[off] = hh; xl[off] = hl;
      }
}

// ---------------- persistent recurrence kernel (counted-vmcnt slab pipeline) ----------------
// 264 launched, 132 active (4 mt x 33 js), 512 thr (8 waves), 1 blk/CU, LDS 144KB.
// Per slab each wave issues EXACTLY 2 global_load_lds (1KB each): A+W both through LDS
// (W in r8's pre-swizzled fragment layout). Ring-8 slots, 7 slabs issued ahead,
// s_waitcnt vmcnt(12) steady (never 0 mid-loop). Flags/term/bias only at drain points.
__launch_bounds__(512)
__global__ void k_recur(_Float16* xh, _Float16* xl,
                        _Float16* h1h0, _Float16* h1l0,
                        _Float16* h1h1, _Float16* h1l1,
                        const _Float16* __restrict__ Wsw0, const _Float16* __restrict__ Wsw1,
                        const float* __restrict__ bias0, const float* __restrict__ bias1,
                        const int* __restrict__ term, int* flags,
                        const _Float16* __restrict__ zp){
  __shared__ _Float16 S[8][8192];      // 8 slots x 16KB: [Ah 4K | Al 4K | Wp0 4K | Wp1 4K]
  __shared__ float gbuf[4][64][16];

  const int tid = threadIdx.x, wv = tid >> 6, l = tid & 63;
  const int b = blockIdx.x;
  const int xcd = b & 7, slot_id = b >> 3;
  int mt, js;
  if (slot_id < 16){ js = xcd + 8*(slot_id >> 2); mt = slot_id & 3; }
  else if (slot_id == 16 && (xcd & 1)){ js = 32; mt = xcd >> 1; }
  else return;
  const int m0 = mt*64, j0 = js*16;

  // ---- staging geometry ----
  const bool isA = (wv < 4);
  const int Apl = wv >> 1;                         // A-waves: 0=hi, 1=lo
  const int rA0 = (wv & 1)*32 + (l >> 2);          // staged A row, instr k=0
  const int rA1 = rA0 + 16;                        // instr k=1
  const int cb0 = (l & 3) ^ ((rA0 >> 1) & 3);      // swizzled source col-block
  const int cb1 = (l & 3) ^ ((rA1 >> 1) & 3);
  const int dA  = Apl*4096 + (wv & 1)*2048;        // LDS byte offset (k=0; k=1 = +1024)
  const int Wp = (wv - 4) >> 1, Whalf = (wv - 4) & 1;  // valid for wv>=4
  const int dW = 8192 + Wp*4096 + Whalf*2048;
  const size_t wlaneoff = (size_t)Whalf*1024 + (size_t)l*8;

  // ---- compute geometry: wave = (m-tile wv&3, gate-pair wv>>2) ----
  const int cp_m = wv & 3, cp_p = wv >> 2, g0 = cp_p*2, mrow = cp_m*16;
  const int fr = mrow + (l & 15);
  const int frbyte = fr*64 + (((l >> 4) ^ ((fr >> 1) & 3)))*16;
  const int wbaseW0 = (js*2 + Wp)*33;              // staging strip base (W-waves)
  const int ep_woff = 8192 + cp_p*4096 + l*16;     // compute-side W base offset

  // ---- epilogue geometry ----
  const int er0 = tid >> 4, ec = tid & 15, er1 = er0 + 32;
  const int jc = j0 + ec;

  float b0r[4], b1r[4];
  #pragma unroll
  for (int g = 0; g < 4; ++g){ b0r[g] = bias0[g*DD + jc]; b1r[g] = bias1[g*DD + jc]; }

  float c1r[2] = {0.f,0.f}, c2r[2] = {0.f,0.f};
  f32x4 accm[2], accc[2];
  bool ndA0, ndA1, ndE0, ndE1;

  auto flag_wait = [&](int idx){
    if (tid == 0){
      while (__hip_atomic_load(&flags[idx], __ATOMIC_RELAXED, __HIP_MEMORY_SCOPE_AGENT) < 33)
        __builtin_amdgcn_s_sleep(2);
    }
    __builtin_amdgcn_s_barrier();
    __builtin_amdgcn_sched_barrier(0);
  };
  auto flag_post = [&](int idx){
    asm volatile("s_waitcnt vmcnt(0)" ::: "memory");
    __builtin_amdgcn_s_barrier();
    if (tid == 0)
      __hip_atomic_fetch_add(&flags[idx], 1, __ATOMIC_RELAXED, __HIP_MEMORY_SCOPE_AGENT);
  };

  auto run_phase = [&](bool isL1,
                       const _Float16* p1h, const _Float16* p1l,
                       const _Float16* p2h, const _Float16* p2l,
                       const _Float16* __restrict__ WswL,
                       int flagStart, int flagMid){
    #pragma unroll
    for (int g = 0; g < 2; ++g)
      #pragma unroll
      for (int q = 0; q < 4; ++q){ accm[g][q]=0.f; accc[g][q]=0.f; }

    const _Float16* P1 = Apl ? p1l : p1h;
    const _Float16* P2 = Apl ? p2l : p2h;

    auto issue = [&](int ii){
      const int s = isL1 ? (ii < 16 ? 17 + ii : (ii < 32 ? ii - 16 : 16)) : ii;
      char* sb = (char*)&S[ii & 7][0];
      if (isA){
        const int col0 = s*32 + cb0*8;
        const int col1 = s*32 + cb1*8;
        const _Float16* s0 = (col0 < DD) ? P1 + (size_t)(m0+rA0)*DD + col0
                           : (ndA0 ? P2 + (size_t)(m0+rA0)*DD + (col0-DD) : zp);
        const _Float16* s1 = (col1 < DD) ? P1 + (size_t)(m0+rA1)*DD + col1
                           : (ndA1 ? P2 + (size_t)(m0+rA1)*DD + (col1-DD) : zp);
        char* d0 = sb + dA;
        char* d1 = d0 + 1024;
        if (isL1 || s >= 16){ GLOAD_LDS(s0, d0, 17); GLOAD_LDS(s1, d1, 17); }
        else                { GLOAD_LDS(s0, d0, 0);  GLOAD_LDS(s1, d1, 0);  }
      } else {
        const _Float16* w0 = WswL + (size_t)(wbaseW0 + s)*2048 + wlaneoff;
        char* d0 = sb + dW;
        GLOAD_LDS(w0,       d0,        0);
        GLOAD_LDS(w0 + 512, d0 + 1024, 0);
      }
    };

    if (flagStart >= 0) flag_wait(flagStart);
    issue(0); issue(1); issue(2); issue(3); issue(4); issue(5); issue(6);

    #pragma unroll 1
    for (int i = 0; i < 33; ++i){
      if (i <= 26)      asm volatile("s_waitcnt vmcnt(12)" ::: "memory");
      else if (i == 27) asm volatile("s_waitcnt vmcnt(10)" ::: "memory");
      else if (i == 28) asm volatile("s_waitcnt vmcnt(8)"  ::: "memory");
      else if (i == 29) asm volatile("s_waitcnt vmcnt(6)"  ::: "memory");
      else if (i == 30) asm volatile("s_waitcnt vmcnt(4)"  ::: "memory");
      else if (i == 31) asm volatile("s_waitcnt vmcnt(2)"  ::: "memory");
      else              asm volatile("s_waitcnt vmcnt(0)"  ::: "memory");
      __builtin_amdgcn_s_barrier();
      __builtin_amdgcn_sched_barrier(0);
      if (i == 9 && flagMid >= 0) flag_wait(flagMid);
      if (i + 7 <= 32) issue(i + 7);
      {
        const char* base = (const char*)&S[i & 7][0];
        half8 fah = *(const half8*)(base + frbyte);
        half8 fal = *(const half8*)(base + 4096 + frbyte);
        const char* wb = base + ep_woff;
        half8 bh0 = *(const half8*)(wb);
        half8 bh1 = *(const half8*)(wb + 1024);
        half8 bl0 = *(const half8*)(wb + 2048);
        half8 bl1 = *(const half8*)(wb + 3072);
        accm[0] = __builtin_amdgcn_mfma_f32_16x16x32_f16(fah, bh0, accm[0], 0, 0, 0);
        accc[0] = __builtin_amdgcn_mfma_f32_16x16x32_f16(fah, bl0, accc[0], 0, 0, 0);
        accc[0] = __builtin_amdgcn_mfma_f32_16x16x32_f16(fal, bh0, accc[0], 0, 0, 0);
        accm[1] = __builtin_amdgcn_mfma_f32_16x16x32_f16(fah, bh1, accm[1], 0, 0, 0);
        accc[1] = __builtin_amdgcn_mfma_f32_16x16x32_f16(fah, bl1, accc[1], 0, 0, 0);
        accc[1] = __builtin_amdgcn_mfma_f32_16x16x32_f16(fal, bh1, accc[1], 0, 0, 0);
      }
    }
  };

  auto epilogue = [&](const float* br, float* cr, _Float16* dh, _Float16* dl){
    #pragma unroll
    for (int gi = 0; gi < 2; ++gi)
      #pragma unroll
      for (int q = 0; q < 4; ++q)
        gbuf[g0 + gi][mrow + (l >> 4)*4 + q][l & 15] = accm[gi][q] + accc[gi][q]*INV_SCL;
    __syncthreads();
    #pragma unroll
    for (int pp = 0; pp < 2; ++pp){
      const int er = pp ? er1 : er0;
      const int row = m0 + er;
      const bool nd = pp ? ndE1 : ndE0;
      float iv = gbuf[0][er][ec] + br[0];
      float fv = gbuf[1][er][ec] + br[1];
      float gv = gbuf[2][er][ec] + br[2];
      float ov = gbuf[3][er][ec] + br[3];
      float cp = nd ? cr[pp] : 0.f;
      float cn = sigf(fv)*cp + sigf(iv)*tanhf(gv);
      float hn = sigf(ov)*tanhf(cn);
      cr[pp] = cn;
      _Float16 hh, hl;
      split1(hn, hh, hl);
      size_t off = (size_t)row*DD + jc;
      __hip_atomic_store((unsigned short*)(dh + off), __builtin_bit_cast(unsigned short, hh),
                         __ATOMIC_RELAXED, __HIP_MEMORY_SCOPE_AGENT);
      __hip_atomic_store((unsigned short*)(dl + off), __builtin_bit_cast(unsigned short, hl),
                         __ATOMIC_RELAXED, __HIP_MEMORY_SCOPE_AGENT);
    }
  };

  _Float16* h1h[2] = {h1h0, h1h1};
  _Float16* h1l[2] = {h1l0, h1l1};

  #pragma unroll 1
  for (int t = 0; t < TT; ++t){
    const int* term_t = term + t*BB;
    ndA0 = (t > 0) && (term_t[m0 + rA0] == 0);
    ndA1 = (t > 0) && (term_t[m0 + rA1] == 0);
    ndE0 = (term_t[m0 + er0] == 0);
    ndE1 = (term_t[m0 + er1] == 0);
    _Float16* xth = xh + (size_t)t*BB*DD;
    _Float16* xtl = xl + (size_t)t*BB*DD;
    const _Float16* xph = xh + (size_t)(t > 0 ? t-1 : 0)*BB*DD;
    const _Float16* xpl = xl + (size_t)(t > 0 ? t-1 : 0)*BB*DD;

    // ===== layer 0: gates = [x(t) | h1(t-1)*nd] @ W0^T =====
    run_phase(false, xth, xtl, h1h[(t+1)&1], h1l[(t+1)&1], Wsw0,
              -1, (t >= 1) ? (t-1)*8 + mt : -1);
    if (t >= 2) flag_wait((t-2)*8 + 4 + mt);           // WAR on h1 buffer t&1
    epilogue(b0r, c1r, h1h[t&1], h1l[t&1]);
    flag_post(t*8 + mt);

    // ===== layer 1: gates = [h1(t) | h2(t-1)*nd] @ W1^T ; h2(t-1)=x[t-1] alias =====
    run_phase(true, h1h[t&1], h1l[t&1], xph, xpl, Wsw1,
              (t >= 1) ? (t-1)*8 + 4 + mt : -1, t*8 + mt);
    epilogue(b1r, c2r, xth, xtl);                      // h2(t) overwrites x[t]
    flag_post(t*8 + 4 + mt);
  }
}

// ---------------- heads: logits/baseline/action ----------------
__launch_bounds__(256)
__global__ void k_heads(const _Float16* __restrict__ oh, const _Float16* __restrict__ ol,
                        const float* __restrict__ polw, const float* __restrict__ basew,
                        const float* __restrict__ polb, const float* __restrict__ baseb,
                        float* __restrict__ dout){
  __shared__ _Float16 Ah[128][40], Al[128][40];
  __shared__ _Float16 Bh[16][552], Bl[16][552];
  const int bid = blockIdx.x;
  const int tid = threadIdx.x, w = tid >> 6, l = tid & 63;
  const int m0 = bid*128;

  for (int i = tid; i < 16*544; i += 256){
    int r = i / 544, c = i % 544;
    float v = 0.f;
    if (c < DD) v = (r < NA) ? polw[r*DD + c] : basew[c];
    split1(v, Bh[r][c], Bl[r][c]);
  }
  __syncthreads();

  f32x4 acc1[2], acc2[2];
  #pragma unroll
  for (int m = 0; m < 2; ++m)
    #pragma unroll
    for (int q = 0; q < 4; ++q){ acc1[m][q]=0.f; acc2[m][q]=0.f; }

  for (int it = 0; it < 17; ++it){
    const int k0 = it*32;
    {
      int row = tid >> 1, c0 = (tid & 1)*16;
      size_t off = (size_t)(m0+row)*DD + k0 + c0;   // overreads pad; B=0 there
      *(half8*)&Ah[row][c0]   = *(const half8*)(oh + off);
      *(half8*)&Ah[row][c0+8] = *(const half8*)(oh + off + 8);
      *(half8*)&Al[row][c0]   = *(const half8*)(ol + off);
      *(half8*)&Al[row][c0+8] = *(const half8*)(ol + off + 8);
    }
    __syncthreads();
    half8 fbh = *(const half8*)&Bh[l & 15][k0 + (l >> 4)*8];
    half8 fbl = *(const half8*)&Bl[l & 15][k0 + (l >> 4)*8];
    #pragma unroll
    for (int m = 0; m < 2; ++m){
      half8 fah = *(const half8*)&Ah[w*32 + m*16 + (l & 15)][(l >> 4)*8];
      half8 fal = *(const half8*)&Al[w*32 + m*16 + (l & 15)][(l >> 4)*8];
      acc1[m] = __builtin_amdgcn_mfma_f32_16x16x32_f16(fah, fbh, acc1[m], 0, 0, 0);
      acc2[m] = __builtin_amdgcn_mfma_f32_16x16x32_f16(fah, fbl, acc2[m], 0, 0, 0);
      acc2[m] = __builtin_amdgcn_mfma_f32_16x16x32_f16(fal, fbh, acc2[m], 0, 0, 0);
    }
    __syncthreads();
  }

  const int a = l & 15;
  const size_t base_off = (size_t)TT*BB*NA;
  const size_t act_off  = base_off + (size_t)TT*BB;
  #pragma unroll
  for (int m = 0; m < 2; ++m)
    #pragma unroll
    for (int q = 0; q < 4; ++q){
      int r = m0 + w*32 + m*16 + (l >> 4)*4 + q;
      float v = acc1[m][q] + acc2[m][q]*INV_SCL + ((a < NA) ? polb[a] : baseb[0]);
      float key = (a < NA) ? v : -3.4e38f;
      int ki = a;
      #pragma unroll
      for (int s = 1; s < 16; s <<= 1){
        float ov = __shfl_xor(key, s, 64);
        int   oi = __shfl_xor(ki,  s, 64);
        if (ov > key || (ov == key && oi < ki)){ key = ov; ki = oi; }
      }
      if (a < NA) dout[(size_t)r*NA + a] = v;
      if (a == NA) dout[base_off + r] = v;
      if (a == 0)  dout[act_off + r] = (float)ki;
    }
}

// ---------------- launch ----------------
extern "C" void kernel_launch(void* const* d_in, const int* in_sizes, int n_in,
                              void* d_out, int out_size, void* d_ws, size_t ws_size,
                              hipStream_t stream){
  const float* obs        = (const float*)d_in[0];
  const int*   last_act   = (const int*)  d_in[1];
  const float* reward     = (const float*)d_in[2];
  const int*   terminated = (const int*)  d_in[3];
  const float* enc_w      = (const float*)d_in[4];
  const float* enc_b      = (const float*)d_in[5];
  const float* w_ih0      = (const float*)d_in[6];
  const float* w_hh0      = (const float*)d_in[7];
  const float* b_ih0      = (const float*)d_in[8];
  const float* b_hh0      = (const float*)d_in[9];
  const float* w_ih1      = (const float*)d_in[10];
  const float* w_hh1      = (const float*)d_in[11];
  const float* b_ih1      = (const float*)d_in[12];
  const float* b_hh1      = (const float*)d_in[13];
  const float* pol_w      = (const float*)d_in[14];
  const float* pol_b      = (const float*)d_in[15];
  const float* base_w     = (const float*)d_in[16];
  const float* base_b     = (const float*)d_in[17];

  char* ws = (char*)d_ws;
  size_t o = 0;
  auto alloc = [&](size_t bytes){ size_t r = o; o += (bytes + 255) & ~(size_t)255; return r; };

  _Float16* Wsw0  = (_Float16*)(ws + alloc((size_t)GG*KK*4));   // hi+lo interleaved
  _Float16* Wsw1  = (_Float16*)(ws + alloc((size_t)GG*KK*4));
  float* bias0    = (float*)(ws + alloc((size_t)GG*4));
  float* bias1    = (float*)(ws + alloc((size_t)GG*4));
  _Float16* ench  = (_Float16*)(ws + alloc((size_t)FEATD*OBSD*2));
  _Float16* encl  = (_Float16*)(ws + alloc((size_t)FEATD*OBSD*2));
  _Float16* xh    = (_Float16*)(ws + alloc((size_t)TT*BB*DD*2 + 4096));  // x / h2-out hi
  _Float16* xl    = (_Float16*)(ws + alloc((size_t)TT*BB*DD*2 + 4096));  // lo plane
  _Float16* h1h0  = (_Float16*)(ws + alloc((size_t)BB*DD*2));
  _Float16* h1l0  = (_Float16*)(ws + alloc((size_t)BB*DD*2));
  _Float16* h1h1  = (_Float16*)(ws + alloc((size_t)BB*DD*2));
  _Float16* h1l1  = (_Float16*)(ws + alloc((size_t)BB*DD*2));
  int*   flags    = (int*)(ws + alloc((size_t)TT*8*4 + 256));   // + zero page
  _Float16* zp    = (_Float16*)((char*)flags + TT*8*4);

  hipMemsetAsync(flags, 0, (size_t)TT*8*4 + 256, stream);

  k_prep_wsw<<<4096, 256, 0, stream>>>(w_ih0, w_hh0, b_ih0, b_hh0, Wsw0, bias0);
  k_prep_wsw<<<4096, 256, 0, stream>>>(w_ih1, w_hh1, b_ih1, b_hh1, Wsw1, bias1);
  k_conv_encw<<<2048, 256, 0, stream>>>(enc_w, ench, encl);
  k_fill_extra<<<TT*BB/256, 256, 0, stream>>>(reward, last_act, xh, xl);

  dim3 eg(TT*BB/128, FEATD/128);
  k_encoder<<<eg, 256, 0, stream>>>(obs, ench, encl, enc_b, xh, xl);

  k_recur<<<264, 512, 0, stream>>>(xh, xl, h1h0, h1l0, h1h1, h1l1,
                                   Wsw0, Wsw1, bias0, bias1,
                                   terminated, flags, zp);

  k_heads<<<TT*BB/128, 256, 0, stream>>>(xh, xl, pol_w, base_w, pol_b, base_b, (float*)d_out);
}

// Round 10
// 3811.799 us; speedup vs baseline: 1.1922x; 1.0453x over previous
//
#include <hip/hip_runtime.h>
#include <hip/hip_bf16.h>

#define TT 128
#define BB 256
#define OBSD 1024
#define FEATD 512
#define NA 15
#define DD 528
#define GG 2112   // 4*DD
#define KK 1056   // 2*DD
#define SCL 4096.f
#define INV_SCL (1.f/4096.f)

using half8 = __attribute__((ext_vector_type(8))) _Float16;
using f32x4 = __attribute__((ext_vector_type(4))) float;

__device__ __forceinline__ void split1(float v, _Float16& h, _Float16& l){
  h = (_Float16)v;
  l = (_Float16)((v - (float)h) * SCL);
}
__device__ __forceinline__ float sigf(float x){ return 1.f/(1.f + expf(-x)); }

// global->LDS direct staging. aux=17 (SC0|SC1): device coherence point (safe vs
// stale per-XCD L2; validated r5-r9). aux=0: normal cached.
#define GLOAD_LDS(g, s, aux) \
  __builtin_amdgcn_global_load_lds((const __attribute__((address_space(1))) void*)(g), \
                                   (__attribute__((address_space(3))) void*)(s), 16, 0, (aux))

// ---------------- prep kernels ----------------

// W pre-swizzled fragment stream: d = ((js*33+s)*2 + plane)*2048 + g*512 + lane*8 + h
// lane: gatecol-local = lane&15, kchunk = lane>>4
__global__ void k_prep_wsw(const float* __restrict__ wih, const float* __restrict__ whh,
                           const float* __restrict__ bih, const float* __restrict__ bhh,
                           _Float16* __restrict__ Wsw, float* __restrict__ bias){
  const int n = 2*GG*KK;
  for (int d = blockIdx.x*blockDim.x + threadIdx.x; d < n; d += gridDim.x*blockDim.x){
    int h     = d & 7;
    int lane  = (d >> 3) & 63;
    int g     = (d >> 9) & 3;
    int plane = (d >> 11) & 1;
    int rest  = d >> 12;          // js*33 + s
    int s  = rest % 33;
    int js = rest / 33;
    int wrow = g*DD + js*16 + (lane & 15);
    int col  = s*32 + (lane >> 4)*8 + h;
    float v = (col < DD) ? wih[wrow*DD + col] : whh[wrow*DD + (col - DD)];
    _Float16 hh, ll; split1(v, hh, ll);
    Wsw[d] = plane ? ll : hh;
    if (d < GG) bias[d] = bih[d] + bhh[d];
  }
}

__global__ void k_conv_encw(const float* __restrict__ src,
                            _Float16* __restrict__ dh, _Float16* __restrict__ dl){
  const int n = FEATD*OBSD;
  for (int i = blockIdx.x*blockDim.x + threadIdx.x; i < n; i += gridDim.x*blockDim.x)
    split1(src[i], dh[i], dl[i]);
}

__global__ void k_fill_extra(const float* __restrict__ reward, const int* __restrict__ act,
                             _Float16* __restrict__ xh, _Float16* __restrict__ xl){
  int row = blockIdx.x*blockDim.x + threadIdx.x;
  if (row >= TT*BB) return;
  float r = fminf(1.f, fmaxf(-1.f, reward[row]));
  size_t base = (size_t)row*DD + FEATD;
  _Float16 hh, hl;
  split1(r, hh, hl);
  xh[base] = hh; xl[base] = hl;
  int a = act[row];
  #pragma unroll
  for (int i = 0; i < NA; ++i){
    xh[base+1+i] = (i == a) ? (_Float16)1.0f : (_Float16)0.0f;
    xl[base+1+i] = (_Float16)0.0f;
  }
}

// ---------------- encoder GEMM -> x planes cols 0..511 ----------------
__launch_bounds__(256)
__global__ void k_encoder(const float* __restrict__ obs, const _Float16* __restrict__ ench,
                          const _Float16* __restrict__ encl,
                          const float* __restrict__ encb,
                          _Float16* __restrict__ xh, _Float16* __restrict__ xl){
  __shared__ _Float16 Ah[128][40], Al[128][40], Bh[128][40], Bl[128][40];
  const int mt = blockIdx.x, nt = blockIdx.y;
  const int tid = threadIdx.x, w = tid >> 6, l = tid & 63;
  const int wm = (w >> 1)*64, wn = (w & 1)*64;
  const int m0 = mt*128, n0 = nt*128;
  f32x4 acc1[4][4], acc2[4][4];
  #pragma unroll
  for (int m = 0; m < 4; ++m)
    #pragma unroll
    for (int n = 0; n < 4; ++n)
      #pragma unroll
      for (int q = 0; q < 4; ++q){ acc1[m][n][q]=0.f; acc2[m][n][q]=0.f; }

  for (int k0 = 0; k0 < OBSD; k0 += 32){
    {
      int row = tid >> 1, c0 = (tid & 1)*16;
      const float* src = obs + (size_t)(m0+row)*OBSD + k0 + c0;
      #pragma unroll
      for (int cc = 0; cc < 16; ++cc){
        float v = src[cc];
        split1(v, Ah[row][c0+cc], Al[row][c0+cc]);
      }
      const _Float16* bh = ench + (size_t)(n0+row)*OBSD + k0 + c0;
      const _Float16* bl = encl + (size_t)(n0+row)*OBSD + k0 + c0;
      *(half8*)&Bh[row][c0]   = *(const half8*)(bh);
      *(half8*)&Bh[row][c0+8] = *(const half8*)(bh+8);
      *(half8*)&Bl[row][c0]   = *(const half8*)(bl);
      *(half8*)&Bl[row][c0+8] = *(const half8*)(bl+8);
    }
    __syncthreads();
    half8 ah[4], al[4], bh[4], bl[4];
    #pragma unroll
    for (int m = 0; m < 4; ++m){
      ah[m] = *(const half8*)&Ah[wm + m*16 + (l & 15)][(l >> 4)*8];
      al[m] = *(const half8*)&Al[wm + m*16 + (l & 15)][(l >> 4)*8];
    }
    #pragma unroll
    for (int n = 0; n < 4; ++n){
      bh[n] = *(const half8*)&Bh[wn + n*16 + (l & 15)][(l >> 4)*8];
      bl[n] = *(const half8*)&Bl[wn + n*16 + (l & 15)][(l >> 4)*8];
    }
    #pragma unroll
    for (int m = 0; m < 4; ++m)
      #pragma unroll
      for (int n = 0; n < 4; ++n){
        acc1[m][n] = __builtin_amdgcn_mfma_f32_16x16x32_f16(ah[m], bh[n], acc1[m][n], 0, 0, 0);
        acc2[m][n] = __builtin_amdgcn_mfma_f32_16x16x32_f16(ah[m], bl[n], acc2[m][n], 0, 0, 0);
        acc2[m][n] = __builtin_amdgcn_mfma_f32_16x16x32_f16(al[m], bh[n], acc2[m][n], 0, 0, 0);
      }
    __syncthreads();
  }
  #pragma unroll
  for (int m = 0; m < 4; ++m)
    #pragma unroll
    for (int n = 0; n < 4; ++n)
      #pragma unroll
      for (int q = 0; q < 4; ++q){
        int row = m0 + wm + m*16 + (l >> 4)*4 + q;
        int col = n0 + wn + n*16 + (l & 15);
        float v = acc1[m][n][q] + acc2[m][n][q]*INV_SCL + encb[col];
        v = fmaxf(v, 0.f);
        _Float16 hh, hl;
        split1(v, hh, hl);
        size_t off = (size_t)row*DD + col;
        xh[off] = hh; xl[off] = hl;
      }
}

// ---------------- persistent recurrence kernel (L0/L1 split block groups) ----------------
// 132 active blocks: (L, mt, js) with L=layer group, mt=128-row half, js=16-col strip.
// G0 (L=0) computes h1(t) for all t; G1 (L=1) computes h2(t). L1(t) runs CONCURRENTLY
// with L0(t+1) on different CUs -> critical path = 128 phases (was 256).
// Per block: 256 thr (4 waves), wave = 32 rows x 4 gates. A+W via 6-slot LDS ring
// (24KB/slab), depth-5, counted vmcnt(24) steady. Flag-gated slabs issued mid-loop.
__launch_bounds__(256)
__global__ void k_recur(_Float16* xh, _Float16* xl,
                        _Float16* h1h0, _Float16* h1l0,
                        _Float16* h1h1, _Float16* h1l1,
                        const _Float16* __restrict__ Wsw0, const _Float16* __restrict__ Wsw1,
                        const float* __restrict__ bias0, const float* __restrict__ bias1,
                        const int* __restrict__ term, int* flags,
                        const _Float16* __restrict__ zp){
  __shared__ char S[6][24576];   // slab: [A-hi 8K | A-lo 8K | W-hi 4K | W-lo 4K]

  const int tid = threadIdx.x, wv = tid >> 6, l = tid & 63;
  const int b = blockIdx.x;
  const int xcd = b & 7, sid = b >> 3;
  int L, mt, js;
  if (sid < 16){ js = xcd + 8*(sid >> 2); int r = sid & 3; L = r >> 1; mt = r & 1; }
  else if (sid == 16 && (xcd & 1)){ js = 32; int r = (xcd - 1) >> 1; L = r >> 1; mt = r & 1; }
  else return;
  const bool isL1 = (L == 1);
  const int m0 = mt*128, j0 = js*16;

  // staging lane geometry (per wave: rows wv*32..+31, 2x 16-row groups, both planes)
  const int r0 = wv*32 + (l >> 2), r1 = r0 + 16;
  const int cb0 = (l & 3) ^ ((r0 >> 1) & 3), cb1 = (l & 3) ^ ((r1 >> 1) & 3);
  // compute geometry
  const int fr0 = wv*32 + (l & 15), fr1 = fr0 + 16;
  const int fb0 = fr0*64 + (((l >> 4) ^ ((fr0 >> 1) & 3)) << 4);
  const int fb1 = fr1*64 + (((l >> 4) ^ ((fr1 >> 1) & 3)) << 4);
  const _Float16* WswL = isL1 ? Wsw1 : Wsw0;
  const float*    biasL = isL1 ? bias1 : bias0;
  // epilogue
  const int ec = l & 15, jc = j0 + ec;
  float br[4];
  #pragma unroll
  for (int g = 0; g < 4; ++g) br[g] = biasL[g*DD + jc];

  float cst[2][4];
  #pragma unroll
  for (int m = 0; m < 2; ++m)
    #pragma unroll
    for (int q = 0; q < 4; ++q) cst[m][q] = 0.f;

  f32x4 accm[4][2], accc[4][2];   // [gate][m-tile]
  bool ndr0 = false, ndr1 = false;

  auto flag_wait = [&](int idx){
    if (tid == 0){
      while (__hip_atomic_load(&flags[idx], __ATOMIC_RELAXED, __HIP_MEMORY_SCOPE_AGENT) < 33)
        __builtin_amdgcn_s_sleep(2);
    }
    __builtin_amdgcn_s_barrier();
    __builtin_amdgcn_sched_barrier(0);
  };
  auto flag_post = [&](int idx){
    asm volatile("s_waitcnt vmcnt(0)" ::: "memory");
    __builtin_amdgcn_s_barrier();
    if (tid == 0)
      __hip_atomic_fetch_add(&flags[idx], 1, __ATOMIC_RELAXED, __HIP_MEMORY_SCOPE_AGENT);
  };

  // one GEMM phase: gates = [p1(528) | p2(528)*mask] @ W^T, 33 K-slabs.
  // G0: p1=x(t) [free, aux0], p2=h1(t-1) [flag fMid, aux17], order s=ii.
  // G1: p1=h1(t) [flag fMid, aux17], p2=h2(t-1)=x(t-1) [flag fStart, aux17],
  //     order: s = ii<16 ? 17+ii : ii<32 ? ii-16 : 16.
  auto run_phase = [&](const _Float16* p1h, const _Float16* p1l,
                       const _Float16* p2h, const _Float16* p2l,
                       int fStart, int fMid){
    #pragma unroll
    for (int g = 0; g < 4; ++g)
      #pragma unroll
      for (int m = 0; m < 2; ++m)
        #pragma unroll
        for (int q = 0; q < 4; ++q){ accm[g][m][q]=0.f; accc[g][m][q]=0.f; }

    auto asrc = [&](int col, int row, bool nd, const _Float16* P1, const _Float16* P2)
        -> const _Float16* {
      if (col < DD) return P1 + (size_t)(m0+row)*DD + col;
      if (isL1 || nd) ; else return zp;
      if (!nd) return zp;
      return P2 + (size_t)(m0+row)*DD + (col - DD);
    };
    auto issue = [&](int ii){
      const int s = isL1 ? (ii < 16 ? 17 + ii : (ii < 32 ? ii - 16 : 16)) : ii;
      char* sb = &S[ii % 6][0];
      const int c0 = s*32 + cb0*8;
      const int c1 = s*32 + cb1*8;
      const _Float16* sh0 = asrc(c0, r0, ndr0, p1h, p2h);
      const _Float16* sh1 = asrc(c1, r1, ndr1, p1h, p2h);
      const _Float16* sl0 = asrc(c0, r0, ndr0, p1l, p2l);
      const _Float16* sl1 = asrc(c1, r1, ndr1, p1l, p2l);
      char* dh0 = sb + wv*2048;
      char* dl0 = sb + 8192 + wv*2048;
      if (isL1 || s >= 16){
        GLOAD_LDS(sh0, dh0, 17);        GLOAD_LDS(sh1, dh0 + 1024, 17);
        GLOAD_LDS(sl0, dl0, 17);        GLOAD_LDS(sl1, dl0 + 1024, 17);
      } else {
        GLOAD_LDS(sh0, dh0, 0);         GLOAD_LDS(sh1, dh0 + 1024, 0);
        GLOAD_LDS(sl0, dl0, 0);         GLOAD_LDS(sl1, dl0 + 1024, 0);
      }
      const _Float16* wsrc = WswL + ((size_t)(js*33 + s)*2)*2048 + wv*512 + l*8;
      GLOAD_LDS(wsrc,        sb + 16384 + wv*1024, 0);
      GLOAD_LDS(wsrc + 2048, sb + 20480 + wv*1024, 0);
    };

    if (fStart >= 0) flag_wait(fStart);
    issue(0); issue(1); issue(2); issue(3); issue(4);

    #pragma unroll 1
    for (int i = 0; i < 33; ++i){
      const int rem = 32 - i;
      if (rem >= 4)      asm volatile("s_waitcnt vmcnt(24)" ::: "memory");
      else if (rem == 3) asm volatile("s_waitcnt vmcnt(18)" ::: "memory");
      else if (rem == 2) asm volatile("s_waitcnt vmcnt(12)" ::: "memory");
      else if (rem == 1) asm volatile("s_waitcnt vmcnt(6)"  ::: "memory");
      else               asm volatile("s_waitcnt vmcnt(0)"  ::: "memory");
      __builtin_amdgcn_s_barrier();
      __builtin_amdgcn_sched_barrier(0);
      if (i == 11 && fMid >= 0) flag_wait(fMid);
      if (i + 5 <= 32) issue(i + 5);
      {
        const char* sb = &S[i % 6][0];
        half8 fah0 = *(const half8*)(sb + fb0);
        half8 fah1 = *(const half8*)(sb + fb1);
        half8 fal0 = *(const half8*)(sb + 8192 + fb0);
        half8 fal1 = *(const half8*)(sb + 8192 + fb1);
        #pragma unroll
        for (int g = 0; g < 4; ++g){
          half8 bh = *(const half8*)(sb + 16384 + g*1024 + l*16);
          half8 bl = *(const half8*)(sb + 20480 + g*1024 + l*16);
          accm[g][0] = __builtin_amdgcn_mfma_f32_16x16x32_f16(fah0, bh, accm[g][0], 0, 0, 0);
          accc[g][0] = __builtin_amdgcn_mfma_f32_16x16x32_f16(fah0, bl, accc[g][0], 0, 0, 0);
          accc[g][0] = __builtin_amdgcn_mfma_f32_16x16x32_f16(fal0, bh, accc[g][0], 0, 0, 0);
          accm[g][1] = __builtin_amdgcn_mfma_f32_16x16x32_f16(fah1, bh, accm[g][1], 0, 0, 0);
          accc[g][1] = __builtin_amdgcn_mfma_f32_16x16x32_f16(fah1, bl, accc[g][1], 0, 0, 0);
          accc[g][1] = __builtin_amdgcn_mfma_f32_16x16x32_f16(fal1, bh, accc[g][1], 0, 0, 0);
        }
      }
    }
  };

  auto epilogue = [&](_Float16* dh, _Float16* dl, const int* term_t){
    #pragma unroll
    for (int m = 0; m < 2; ++m)
      #pragma unroll
      for (int q = 0; q < 4; ++q){
        const int row = m0 + wv*32 + m*16 + (l >> 4)*4 + q;
        float iv = accm[0][m][q] + accc[0][m][q]*INV_SCL + br[0];
        float fv = accm[1][m][q] + accc[1][m][q]*INV_SCL + br[1];
        float gv = accm[2][m][q] + accc[2][m][q]*INV_SCL + br[2];
        float ov = accm[3][m][q] + accc[3][m][q]*INV_SCL + br[3];
        float cp = (term_t[row] == 0) ? cst[m][q] : 0.f;
        float cn = sigf(fv)*cp + sigf(iv)*tanhf(gv);
        float hn = sigf(ov)*tanhf(cn);
        cst[m][q] = cn;
        _Float16 hh, hl;
        split1(hn, hh, hl);
        size_t off = (size_t)row*DD + jc;
        __hip_atomic_store((unsigned short*)(dh + off), __builtin_bit_cast(unsigned short, hh),
                           __ATOMIC_RELAXED, __HIP_MEMORY_SCOPE_AGENT);
        __hip_atomic_store((unsigned short*)(dl + off), __builtin_bit_cast(unsigned short, hl),
                           __ATOMIC_RELAXED, __HIP_MEMORY_SCOPE_AGENT);
      }
  };

  _Float16* h1h[2] = {h1h0, h1h1};
  _Float16* h1l[2] = {h1l0, h1l1};

  if (!isL1){
    // ===== G0: h1(t) = LSTM0([x(t) | h1(t-1)*nd]) =====
    #pragma unroll 1
    for (int t = 0; t < TT; ++t){
      const int* term_t = term + t*BB;
      ndr0 = (t > 0) && (term_t[m0 + r0] == 0);
      ndr1 = (t > 0) && (term_t[m0 + r1] == 0);
      run_phase(xh + (size_t)t*BB*DD, xl + (size_t)t*BB*DD,
                h1h[(t+1)&1], h1l[(t+1)&1],
                -1, (t >= 1) ? (t-1)*4 + mt : -1);
      if (t >= 2) flag_wait((t-2)*4 + 2 + mt);   // WAR: G1(t-2) done reading h1[t&1]
      epilogue(h1h[t&1], h1l[t&1], term_t);
      flag_post(t*4 + mt);
    }
  } else {
    // ===== G1: h2(t) = LSTM1([h1(t) | h2(t-1)*nd]) ; h2 stored into x[t] =====
    #pragma unroll 1
    for (int t = 0; t < TT; ++t){
      const int* term_t = term + t*BB;
      ndr0 = (t > 0) && (term_t[m0 + r0] == 0);
      ndr1 = (t > 0) && (term_t[m0 + r1] == 0);
      run_phase(h1h[t&1], h1l[t&1],
                xh + (size_t)(t > 0 ? t-1 : 0)*BB*DD, xl + (size_t)(t > 0 ? t-1 : 0)*BB*DD,
                (t >= 1) ? (t-1)*4 + 2 + mt : -1, t*4 + mt);
      epilogue(xh + (size_t)t*BB*DD, xl + (size_t)t*BB*DD, term_t);
      flag_post(t*4 + 2 + mt);
    }
  }
}

// ---------------- heads: logits/baseline/action ----------------
__launch_bounds__(256)
__global__ void k_heads(const _Float16* __restrict__ oh, const _Float16* __restrict__ ol,
                        const float* __restrict__ polw, const float* __restrict__ basew,
                        const float* __restrict__ polb, const float* __restrict__ baseb,
                        float* __restrict__ dout){
  __shared__ _Float16 Ah[128][40], Al[128][40];
  __shared__ _Float16 Bh[16][552], Bl[16][552];
  const int bid = blockIdx.x;
  const int tid = threadIdx.x, w = tid >> 6, l = tid & 63;
  const int m0 = bid*128;

  for (int i = tid; i < 16*544; i += 256){
    int r = i / 544, c = i % 544;
    float v = 0.f;
    if (c < DD) v = (r < NA) ? polw[r*DD + c] : basew[c];
    split1(v, Bh[r][c], Bl[r][c]);
  }
  __syncthreads();

  f32x4 acc1[2], acc2[2];
  #pragma unroll
  for (int m = 0; m < 2; ++m)
    #pragma unroll
    for (int q = 0; q < 4; ++q){ acc1[m][q]=0.f; acc2[m][q]=0.f; }

  for (int it = 0; it < 17; ++it){
    const int k0 = it*32;
    {
      int row = tid >> 1, c0 = (tid & 1)*16;
      size_t off = (size_t)(m0+row)*DD + k0 + c0;   // overreads pad; B=0 there
      *(half8*)&Ah[row][c0]   = *(const half8*)(oh + off);
      *(half8*)&Ah[row][c0+8] = *(const half8*)(oh + off + 8);
      *(half8*)&Al[row][c0]   = *(const half8*)(ol + off);
      *(half8*)&Al[row][c0+8] = *(const half8*)(ol + off + 8);
    }
    __syncthreads();
    half8 fbh = *(const half8*)&Bh[l & 15][k0 + (l >> 4)*8];
    half8 fbl = *(const half8*)&Bl[l & 15][k0 + (l >> 4)*8];
    #pragma unroll
    for (int m = 0; m < 2; ++m){
      half8 fah = *(const half8*)&Ah[w*32 + m*16 + (l & 15)][(l >> 4)*8];
      half8 fal = *(const half8*)&Al[w*32 + m*16 + (l & 15)][(l >> 4)*8];
      acc1[m] = __builtin_amdgcn_mfma_f32_16x16x32_f16(fah, fbh, acc1[m], 0, 0, 0);
      acc2[m] = __builtin_amdgcn_mfma_f32_16x16x32_f16(fah, fbl, acc2[m], 0, 0, 0);
      acc2[m] = __builtin_amdgcn_mfma_f32_16x16x32_f16(fal, fbh, acc2[m], 0, 0, 0);
    }
    __syncthreads();
  }

  const int a = l & 15;
  const size_t base_off = (size_t)TT*BB*NA;
  const size_t act_off  = base_off + (size_t)TT*BB;
  #pragma unroll
  for (int m = 0; m < 2; ++m)
    #pragma unroll
    for (int q = 0; q < 4; ++q){
      int r = m0 + w*32 + m*16 + (l >> 4)*4 + q;
      float v = acc1[m][q] + acc2[m][q]*INV_SCL + ((a < NA) ? polb[a] : baseb[0]);
      float key = (a < NA) ? v : -3.4e38f;
      int ki = a;
      #pragma unroll
      for (int s = 1; s < 16; s <<= 1){
        float ov = __shfl_xor(key, s, 64);
        int   oi = __shfl_xor(ki,  s, 64);
        if (ov > key || (ov == key && oi < ki)){ key = ov; ki = oi; }
      }
      if (a < NA) dout[(size_t)r*NA + a] = v;
      if (a == NA) dout[base_off + r] = v;
      if (a == 0)  dout[act_off + r] = (float)ki;
    }
}

// ---------------- launch ----------------
extern "C" void kernel_launch(void* const* d_in, const int* in_sizes, int n_in,
                              void* d_out, int out_size, void* d_ws, size_t ws_size,
                              hipStream_t stream){
  const float* obs        = (const float*)d_in[0];
  const int*   last_act   = (const int*)  d_in[1];
  const float* reward     = (const float*)d_in[2];
  const int*   terminated = (const int*)  d_in[3];
  const float* enc_w      = (const float*)d_in[4];
  const float* enc_b      = (const float*)d_in[5];
  const float* w_ih0      = (const float*)d_in[6];
  const float* w_hh0      = (const float*)d_in[7];
  const float* b_ih0      = (const float*)d_in[8];
  const float* b_hh0      = (const float*)d_in[9];
  const float* w_ih1      = (const float*)d_in[10];
  const float* w_hh1      = (const float*)d_in[11];
  const float* b_ih1      = (const float*)d_in[12];
  const float* b_hh1      = (const float*)d_in[13];
  const float* pol_w      = (const float*)d_in[14];
  const float* pol_b      = (const float*)d_in[15];
  const float* base_w     = (const float*)d_in[16];
  const float* base_b     = (const float*)d_in[17];

  char* ws = (char*)d_ws;
  size_t o = 0;
  auto alloc = [&](size_t bytes){ size_t r = o; o += (bytes + 255) & ~(size_t)255; return r; };

  _Float16* Wsw0  = (_Float16*)(ws + alloc((size_t)GG*KK*4));   // hi+lo planes
  _Float16* Wsw1  = (_Float16*)(ws + alloc((size_t)GG*KK*4));
  float* bias0    = (float*)(ws + alloc((size_t)GG*4));
  float* bias1    = (float*)(ws + alloc((size_t)GG*4));
  _Float16* ench  = (_Float16*)(ws + alloc((size_t)FEATD*OBSD*2));
  _Float16* encl  = (_Float16*)(ws + alloc((size_t)FEATD*OBSD*2));
  _Float16* xh    = (_Float16*)(ws + alloc((size_t)TT*BB*DD*2 + 4096));  // x / h2-out hi
  _Float16* xl    = (_Float16*)(ws + alloc((size_t)TT*BB*DD*2 + 4096));  // lo plane
  _Float16* h1h0  = (_Float16*)(ws + alloc((size_t)BB*DD*2));
  _Float16* h1l0  = (_Float16*)(ws + alloc((size_t)BB*DD*2));
  _Float16* h1h1  = (_Float16*)(ws + alloc((size_t)BB*DD*2));
  _Float16* h1l1  = (_Float16*)(ws + alloc((size_t)BB*DD*2));
  int*   flags    = (int*)(ws + alloc((size_t)TT*4*4 + 256));   // + zero page
  _Float16* zp    = (_Float16*)((char*)flags + TT*4*4);

  hipMemsetAsync(flags, 0, (size_t)TT*4*4 + 256, stream);

  k_prep_wsw<<<4096, 256, 0, stream>>>(w_ih0, w_hh0, b_ih0, b_hh0, Wsw0, bias0);
  k_prep_wsw<<<4096, 256, 0, stream>>>(w_ih1, w_hh1, b_ih1, b_hh1, Wsw1, bias1);
  k_conv_encw<<<2048, 256, 0, stream>>>(enc_w, ench, encl);
  k_fill_extra<<<TT*BB/256, 256, 0, stream>>>(reward, last_act, xh, xl);

  dim3 eg(TT*BB/128, FEATD/128);
  k_encoder<<<eg, 256, 0, stream>>>(obs, ench, encl, enc_b, xh, xl);

  k_recur<<<264, 256, 0, stream>>>(xh, xl, h1h0, h1l0, h1h1, h1l1,
                                   Wsw0, Wsw1, bias0, bias1,
                                   terminated, flags, zp);

  k_heads<<<TT*BB/128, 256, 0, stream>>>(xh, xl, pol_w, base_w, pol_b, base_b, (float*)d_out);
}

// Round 14
// 3360.979 us; speedup vs baseline: 1.3521x; 1.1341x over previous
//
#include <hip/hip_runtime.h>
#include <hip/hip_bf16.h>

#define TT 128
#define BB 256
#define OBSD 1024
#define FEATD 512
#define NA 15
#define DD 528
#define GG 2112   // 4*DD
#define KK 1056   // 2*DD
#define SCL 4096.f
#define INV_SCL (1.f/4096.f)

using half8 = __attribute__((ext_vector_type(8))) _Float16;
using f32x4 = __attribute__((ext_vector_type(4))) float;

__device__ __forceinline__ void split1(float v, _Float16& h, _Float16& l){
  h = (_Float16)v;
  l = (_Float16)((v - (float)h) * SCL);
}
__device__ __forceinline__ float sigf(float x){ return 1.f/(1.f + expf(-x)); }

// global->LDS direct staging. aux=17 (SC0|SC1): device coherence point (safe vs
// stale per-XCD L2; validated r5-r10). aux=0: normal cached.
#define GLOAD_LDS(g, s, aux) \
  __builtin_amdgcn_global_load_lds((const __attribute__((address_space(1))) void*)(g), \
                                   (__attribute__((address_space(3))) void*)(s), 16, 0, (aux))

// ---------------- prep kernels ----------------

// W pre-swizzled fragment stream: d = ((js*33+s)*2 + plane)*2048 + g*512 + lane*8
__global__ void k_prep_wsw(const float* __restrict__ wih, const float* __restrict__ whh,
                           const float* __restrict__ bih, const float* __restrict__ bhh,
                           _Float16* __restrict__ Wsw, float* __restrict__ bias){
  const int n = 2*GG*KK;
  for (int d = blockIdx.x*blockDim.x + threadIdx.x; d < n; d += gridDim.x*blockDim.x){
    int h     = d & 7;
    int lane  = (d >> 3) & 63;
    int g     = (d >> 9) & 3;
    int plane = (d >> 11) & 1;
    int rest  = d >> 12;          // js*33 + s
    int s  = rest % 33;
    int js = rest / 33;
    int wrow = g*DD + js*16 + (lane & 15);
    int col  = s*32 + (lane >> 4)*8 + h;
    float v = (col < DD) ? wih[wrow*DD + col] : whh[wrow*DD + (col - DD)];
    _Float16 hh, ll; split1(v, hh, ll);
    Wsw[d] = plane ? ll : hh;
    if (d < GG) bias[d] = bih[d] + bhh[d];
  }
}

__global__ void k_conv_encw(const float* __restrict__ src,
                            _Float16* __restrict__ dh, _Float16* __restrict__ dl){
  const int n = FEATD*OBSD;
  for (int i = blockIdx.x*blockDim.x + threadIdx.x; i < n; i += gridDim.x*blockDim.x)
    split1(src[i], dh[i], dl[i]);
}

__global__ void k_fill_extra(const float* __restrict__ reward, const int* __restrict__ act,
                             _Float16* __restrict__ xh, _Float16* __restrict__ xl){
  int row = blockIdx.x*blockDim.x + threadIdx.x;
  if (row >= TT*BB) return;
  float r = fminf(1.f, fmaxf(-1.f, reward[row]));
  size_t base = (size_t)row*DD + FEATD;
  _Float16 hh, hl;
  split1(r, hh, hl);
  xh[base] = hh; xl[base] = hl;
  int a = act[row];
  #pragma unroll
  for (int i = 0; i < NA; ++i){
    xh[base+1+i] = (i == a) ? (_Float16)1.0f : (_Float16)0.0f;
    xl[base+1+i] = (_Float16)0.0f;
  }
}

// ---------------- encoder GEMM -> x planes cols 0..511 ----------------
__launch_bounds__(256)
__global__ void k_encoder(const float* __restrict__ obs, const _Float16* __restrict__ ench,
                          const _Float16* __restrict__ encl,
                          const float* __restrict__ encb,
                          _Float16* __restrict__ xh, _Float16* __restrict__ xl){
  __shared__ _Float16 Ah[128][40], Al[128][40], Bh[128][40], Bl[128][40];
  const int mt = blockIdx.x, nt = blockIdx.y;
  const int tid = threadIdx.x, w = tid >> 6, l = tid & 63;
  const int wm = (w >> 1)*64, wn = (w & 1)*64;
  const int m0 = mt*128, n0 = nt*128;
  f32x4 acc1[4][4], acc2[4][4];
  #pragma unroll
  for (int m = 0; m < 4; ++m)
    #pragma unroll
    for (int n = 0; n < 4; ++n)
      #pragma unroll
      for (int q = 0; q < 4; ++q){ acc1[m][n][q]=0.f; acc2[m][n][q]=0.f; }

  for (int k0 = 0; k0 < OBSD; k0 += 32){
    {
      int row = tid >> 1, c0 = (tid & 1)*16;
      const float* src = obs + (size_t)(m0+row)*OBSD + k0 + c0;
      #pragma unroll
      for (int cc = 0; cc < 16; ++cc){
        float v = src[cc];
        split1(v, Ah[row][c0+cc], Al[row][c0+cc]);
      }
      const _Float16* bh = ench + (size_t)(n0+row)*OBSD + k0 + c0;
      const _Float16* bl = encl + (size_t)(n0+row)*OBSD + k0 + c0;
      *(half8*)&Bh[row][c0]   = *(const half8*)(bh);
      *(half8*)&Bh[row][c0+8] = *(const half8*)(bh+8);
      *(half8*)&Bl[row][c0]   = *(const half8*)(bl);
      *(half8*)&Bl[row][c0+8] = *(const half8*)(bl+8);
    }
    __syncthreads();
    half8 ah[4], al[4], bh[4], bl[4];
    #pragma unroll
    for (int m = 0; m < 4; ++m){
      ah[m] = *(const half8*)&Ah[wm + m*16 + (l & 15)][(l >> 4)*8];
      al[m] = *(const half8*)&Al[wm + m*16 + (l & 15)][(l >> 4)*8];
    }
    #pragma unroll
    for (int n = 0; n < 4; ++n){
      bh[n] = *(const half8*)&Bh[wn + n*16 + (l & 15)][(l >> 4)*8];
      bl[n] = *(const half8*)&Bl[wn + n*16 + (l & 15)][(l >> 4)*8];
    }
    #pragma unroll
    for (int m = 0; m < 4; ++m)
      #pragma unroll
      for (int n = 0; n < 4; ++n){
        acc1[m][n] = __builtin_amdgcn_mfma_f32_16x16x32_f16(ah[m], bh[n], acc1[m][n], 0, 0, 0);
        acc2[m][n] = __builtin_amdgcn_mfma_f32_16x16x32_f16(ah[m], bl[n], acc2[m][n], 0, 0, 0);
        acc2[m][n] = __builtin_amdgcn_mfma_f32_16x16x32_f16(al[m], bh[n], acc2[m][n], 0, 0, 0);
      }
    __syncthreads();
  }
  #pragma unroll
  for (int m = 0; m < 4; ++m)
    #pragma unroll
    for (int n = 0; n < 4; ++n)
      #pragma unroll
      for (int q = 0; q < 4; ++q){
        int row = m0 + wm + m*16 + (l >> 4)*4 + q;
        int col = n0 + wn + n*16 + (l & 15);
        float v = acc1[m][n][q] + acc2[m][n][q]*INV_SCL + encb[col];
        v = fmaxf(v, 0.f);
        _Float16 hh, hl;
        split1(v, hh, hl);
        size_t off = (size_t)row*DD + col;
        xh[off] = hh; xl[off] = hl;
      }
}

// ---------------- persistent recurrence kernel (r10 protocol, 64-row tiles) ----------------
// 264 blocks = (L, mt 0..3 [64 rows], js 0..32), 256 thr (4 waves), LDS 80KB ->
// 2 blocks/CU capacity, all 264 resident.
// Wave wv: stages A rows wv*16..+15 (both planes, 2 loads) + W quarter wv
// (2 loads, WITH per-lane +l*8 term - r13's bug was a uniform W source addr),
// computes its 16 rows x all 4 gates. 5-slot LDS ring, depth-4 issue,
// vmcnt 12/8/4/0 ladder, one barrier/slab, fMid gate at i==12 before issue(16).
__launch_bounds__(256, 2)
__global__ void k_recur(_Float16* xh, _Float16* xl,
                        _Float16* h1h0, _Float16* h1l0,
                        _Float16* h1h1, _Float16* h1l1,
                        const _Float16* __restrict__ Wsw0, const _Float16* __restrict__ Wsw1,
                        const float* __restrict__ bias0, const float* __restrict__ bias1,
                        const int* __restrict__ term, int* flags,
                        const _Float16* __restrict__ zp){
  __shared__ char S[5][16384];   // slab: [A-hi 4K | A-lo 4K | W-hi 4K | W-lo 4K]

  const int tid = threadIdx.x, wv = tid >> 6, l = tid & 63;
  const int b = blockIdx.x;
  const int xcd = b & 7, slot = b >> 3;   // 0..32
  int L, mt, js;
  if (slot < 32){ js = xcd + 8*(slot >> 3); const int u = slot & 7; L = u >> 2; mt = u & 3; }
  else          { js = 32; L = xcd >> 2; mt = xcd & 3; }
  const bool isL1 = (L == 1);
  const int m0 = mt*64, j0 = js*16;

  // staging geometry: wave wv -> rows wv*16..+15, 4 lanes/row
  const int arow = wv*16 + (l >> 2);
  const int acb  = (l & 3) ^ ((arow >> 1) & 3);      // swizzled src col-block
  // compute geometry: wave wv -> rows wv*16..+15 x all 4 gates
  const int Rf  = wv*16 + (l & 15);
  const int fbo = Rf*64 + (((l >> 4) ^ ((Rf >> 1) & 3)) << 4);
  // epilogue
  const int jc = j0 + (l & 15);

  const _Float16* WswL = isL1 ? Wsw1 : Wsw0;
  const float* biasL = isL1 ? bias1 : bias0;
  float br[4];
  #pragma unroll
  for (int g = 0; g < 4; ++g) br[g] = biasL[g*DD + jc];

  float cst[4] = {0.f, 0.f, 0.f, 0.f};
  f32x4 accm[4], accc[4];
  bool ndr = false;

  auto flag_wait = [&](int idx){
    if (tid == 0){
      while (__hip_atomic_load(&flags[idx], __ATOMIC_RELAXED, __HIP_MEMORY_SCOPE_AGENT) < 33)
        __builtin_amdgcn_s_sleep(2);
    }
    __builtin_amdgcn_s_barrier();
    __builtin_amdgcn_sched_barrier(0);
  };
  auto post = [&](int idx){
    asm volatile("s_waitcnt vmcnt(0)" ::: "memory");
    __builtin_amdgcn_s_barrier();
    if (tid == 0)
      __hip_atomic_fetch_add(&flags[idx], 1, __ATOMIC_RELAXED, __HIP_MEMORY_SCOPE_AGENT);
  };

  auto run_phase = [&](const _Float16* p1h, const _Float16* p1l,
                       const _Float16* p2h, const _Float16* p2l,
                       int fStart, int fMid){
    #pragma unroll
    for (int g = 0; g < 4; ++g)
      #pragma unroll
      for (int q = 0; q < 4; ++q){ accm[g][q] = 0.f; accc[g][q] = 0.f; }

    auto sOf = [&](int ii){ return isL1 ? (ii < 16 ? 17 + ii : (ii < 32 ? ii - 16 : 16)) : ii; };
    auto issue = [&](int ii){
      const int s = sOf(ii);
      char* sb = &S[ii % 5][0];
      const int col = s*32 + acb*8;
      const _Float16 *sh, *sl;
      if (col < DD){
        sh = p1h + (size_t)(m0 + arow)*DD + col;
        sl = p1l + (size_t)(m0 + arow)*DD + col;
      } else if (ndr){
        sh = p2h + (size_t)(m0 + arow)*DD + (col - DD);
        sl = p2l + (size_t)(m0 + arow)*DD + (col - DD);
      } else {
        sh = zp; sl = zp;
      }
      char* dhi = sb + wv*1024;
      char* dlo = sb + 4096 + wv*1024;
      if (isL1 || s >= 16){ GLOAD_LDS(sh, dhi, 17); GLOAD_LDS(sl, dlo, 17); }
      else                { GLOAD_LDS(sh, dhi, 0);  GLOAD_LDS(sl, dlo, 0);  }
      // W: per-lane source address (uniform-addr bug in r13: missing + l*8)
      const _Float16* w = WswL + (size_t)(js*33 + s)*4096 + wv*1024 + l*8;
      GLOAD_LDS(w,       sb + 8192 + wv*2048, 0);
      GLOAD_LDS(w + 512, sb + 8192 + wv*2048 + 1024, 0);
    };

    if (fStart >= 0) flag_wait(fStart);
    issue(0); issue(1); issue(2); issue(3);

    #pragma unroll 1
    for (int i = 0; i < 33; ++i){
      const int rem = 32 - i;
      if (rem >= 3)      asm volatile("s_waitcnt vmcnt(12)" ::: "memory");
      else if (rem == 2) asm volatile("s_waitcnt vmcnt(8)"  ::: "memory");
      else if (rem == 1) asm volatile("s_waitcnt vmcnt(4)"  ::: "memory");
      else               asm volatile("s_waitcnt vmcnt(0)"  ::: "memory");
      __builtin_amdgcn_s_barrier();
      __builtin_amdgcn_sched_barrier(0);
      // gate the dependent half BEFORE slab ii=16 is issued (depth-4: at i=12)
      if (i == 12 && fMid >= 0) flag_wait(fMid);
      if (i + 4 <= 32) issue(i + 4);
      {
        const char* sb = &S[i % 5][0];
        half8 fah = *(const half8*)(sb + fbo);
        half8 fal = *(const half8*)(sb + 4096 + fbo);
        #pragma unroll
        for (int g = 0; g < 4; ++g){
          half8 bh = *(const half8*)(sb + 8192 + g*1024 + l*16);
          half8 bl = *(const half8*)(sb + 12288 + g*1024 + l*16);
          accm[g] = __builtin_amdgcn_mfma_f32_16x16x32_f16(fah, bh, accm[g], 0, 0, 0);
          accc[g] = __builtin_amdgcn_mfma_f32_16x16x32_f16(fah, bl, accc[g], 0, 0, 0);
          accc[g] = __builtin_amdgcn_mfma_f32_16x16x32_f16(fal, bh, accc[g], 0, 0, 0);
        }
      }
    }
  };

  auto epilogue = [&](_Float16* dh, _Float16* dl, const int* term_t, int warFlag){
    if (warFlag >= 0) flag_wait(warFlag);
    #pragma unroll
    for (int q = 0; q < 4; ++q){
      const int row = m0 + wv*16 + (l >> 4)*4 + q;
      float iv = accm[0][q] + accc[0][q]*INV_SCL + br[0];
      float fv = accm[1][q] + accc[1][q]*INV_SCL + br[1];
      float gv = accm[2][q] + accc[2][q]*INV_SCL + br[2];
      float ov = accm[3][q] + accc[3][q]*INV_SCL + br[3];
      float cp = (term_t[row] == 0) ? cst[q] : 0.f;
      float cn = sigf(fv)*cp + sigf(iv)*tanhf(gv);
      float hn = sigf(ov)*tanhf(cn);
      cst[q] = cn;
      _Float16 hh, hl;
      split1(hn, hh, hl);
      size_t off = (size_t)row*DD + jc;
      __hip_atomic_store((unsigned short*)(dh + off), __builtin_bit_cast(unsigned short, hh),
                         __ATOMIC_RELAXED, __HIP_MEMORY_SCOPE_AGENT);
      __hip_atomic_store((unsigned short*)(dl + off), __builtin_bit_cast(unsigned short, hl),
                         __ATOMIC_RELAXED, __HIP_MEMORY_SCOPE_AGENT);
    }
  };

  _Float16* h1h[2] = {h1h0, h1h1};
  _Float16* h1l[2] = {h1l0, h1l1};

  if (!isL1){
    // ===== G0: h1(t) = LSTM0([x(t) | h1(t-1)*nd]) =====
    #pragma unroll 1
    for (int t = 0; t < TT; ++t){
      const int* term_t = term + t*BB;
      ndr = (t > 0) && (term_t[m0 + arow] == 0);
      run_phase(xh + (size_t)t*BB*DD, xl + (size_t)t*BB*DD,
                h1h[(t+1)&1], h1l[(t+1)&1],
                -1, (t >= 1) ? (t-1)*8 + mt : -1);
      // WAR: G1(t-2) done reading h1 buffer [t&1]
      epilogue(h1h[t&1], h1l[t&1], term_t, (t >= 2) ? (t-2)*8 + 4 + mt : -1);
      post(t*8 + mt);
    }
  } else {
    // ===== G1: h2(t) = LSTM1([h1(t) | h2(t-1)*nd]) ; h2 stored into x[t] =====
    #pragma unroll 1
    for (int t = 0; t < TT; ++t){
      const int* term_t = term + t*BB;
      ndr = (t > 0) && (term_t[m0 + arow] == 0);
      run_phase(h1h[t&1], h1l[t&1],
                xh + (size_t)(t > 0 ? t-1 : 0)*BB*DD, xl + (size_t)(t > 0 ? t-1 : 0)*BB*DD,
                (t >= 1) ? (t-1)*8 + 4 + mt : -1, t*8 + mt);
      epilogue(xh + (size_t)t*BB*DD, xl + (size_t)t*BB*DD, term_t, -1);
      post(t*8 + 4 + mt);
    }
  }
}

// ---------------- heads: logits/baseline/action ----------------
__launch_bounds__(256)
__global__ void k_heads(const _Float16* __restrict__ oh, const _Float16* __restrict__ ol,
                        const float* __restrict__ polw, const float* __restrict__ basew,
                        const float* __restrict__ polb, const float* __restrict__ baseb,
                        float* __restrict__ dout){
  __shared__ _Float16 Ah[128][40], Al[128][40];
  __shared__ _Float16 Bh[16][552], Bl[16][552];
  const int bid = blockIdx.x;
  const int tid = threadIdx.x, w = tid >> 6, l = tid & 63;
  const int m0 = bid*128;

  for (int i = tid; i < 16*544; i += 256){
    int r = i / 544, c = i % 544;
    float v = 0.f;
    if (c < DD) v = (r < NA) ? polw[r*DD + c] : basew[c];
    split1(v, Bh[r][c], Bl[r][c]);
  }
  __syncthreads();

  f32x4 acc1[2], acc2[2];
  #pragma unroll
  for (int m = 0; m < 2; ++m)
    #pragma unroll
    for (int q = 0; q < 4; ++q){ acc1[m][q]=0.f; acc2[m][q]=0.f; }

  for (int it = 0; it < 17; ++it){
    const int k0 = it*32;
    {
      int row = tid >> 1, c0 = (tid & 1)*16;
      size_t off = (size_t)(m0+row)*DD + k0 + c0;   // overreads pad; B=0 there
      *(half8*)&Ah[row][c0]   = *(const half8*)(oh + off);
      *(half8*)&Ah[row][c0+8] = *(const half8*)(oh + off + 8);
      *(half8*)&Al[row][c0]   = *(const half8*)(ol + off);
      *(half8*)&Al[row][c0+8] = *(const half8*)(ol + off + 8);
    }
    __syncthreads();
    half8 fbh = *(const half8*)&Bh[l & 15][k0 + (l >> 4)*8];
    half8 fbl = *(const half8*)&Bl[l & 15][k0 + (l >> 4)*8];
    #pragma unroll
    for (int m = 0; m < 2; ++m){
      half8 fah = *(const half8*)&Ah[w*32 + m*16 + (l & 15)][(l >> 4)*8];
      half8 fal = *(const half8*)&Al[w*32 + m*16 + (l & 15)][(l >> 4)*8];
      acc1[m] = __builtin_amdgcn_mfma_f32_16x16x32_f16(fah, fbh, acc1[m], 0, 0, 0);
      acc2[m] = __builtin_amdgcn_mfma_f32_16x16x32_f16(fah, fbl, acc2[m], 0, 0, 0);
      acc2[m] = __builtin_amdgcn_mfma_f32_16x16x32_f16(fal, fbh, acc2[m], 0, 0, 0);
    }
    __syncthreads();
  }

  const int a = l & 15;
  const size_t base_off = (size_t)TT*BB*NA;
  const size_t act_off  = base_off + (size_t)TT*BB;
  #pragma unroll
  for (int m = 0; m < 2; ++m)
    #pragma unroll
    for (int q = 0; q < 4; ++q){
      int r = m0 + w*32 + m*16 + (l >> 4)*4 + q;
      float v = acc1[m][q] + acc2[m][q]*INV_SCL + ((a < NA) ? polb[a] : baseb[0]);
      float key = (a < NA) ? v : -3.4e38f;
      int ki = a;
      #pragma unroll
      for (int s = 1; s < 16; s <<= 1){
        float ov = __shfl_xor(key, s, 64);
        int   oi = __shfl_xor(ki,  s, 64);
        if (ov > key || (ov == key && oi < ki)){ key = ov; ki = oi; }
      }
      if (a < NA) dout[(size_t)r*NA + a] = v;
      if (a == NA) dout[base_off + r] = v;
      if (a == 0)  dout[act_off + r] = (float)ki;
    }
}

// ---------------- launch ----------------
extern "C" void kernel_launch(void* const* d_in, const int* in_sizes, int n_in,
                              void* d_out, int out_size, void* d_ws, size_t ws_size,
                              hipStream_t stream){
  const float* obs        = (const float*)d_in[0];
  const int*   last_act   = (const int*)  d_in[1];
  const float* reward     = (const float*)d_in[2];
  const int*   terminated = (const int*)  d_in[3];
  const float* enc_w      = (const float*)d_in[4];
  const float* enc_b      = (const float*)d_in[5];
  const float* w_ih0      = (const float*)d_in[6];
  const float* w_hh0      = (const float*)d_in[7];
  const float* b_ih0      = (const float*)d_in[8];
  const float* b_hh0      = (const float*)d_in[9];
  const float* w_ih1      = (const float*)d_in[10];
  const float* w_hh1      = (const float*)d_in[11];
  const float* b_ih1      = (const float*)d_in[12];
  const float* b_hh1      = (const float*)d_in[13];
  const float* pol_w      = (const float*)d_in[14];
  const float* pol_b      = (const float*)d_in[15];
  const float* base_w     = (const float*)d_in[16];
  const float* base_b     = (const float*)d_in[17];

  char* ws = (char*)d_ws;
  size_t o = 0;
  auto alloc = [&](size_t bytes){ size_t r = o; o += (bytes + 255) & ~(size_t)255; return r; };

  _Float16* Wsw0  = (_Float16*)(ws + alloc((size_t)GG*KK*4));   // hi+lo planes
  _Float16* Wsw1  = (_Float16*)(ws + alloc((size_t)GG*KK*4));
  float* bias0    = (float*)(ws + alloc((size_t)GG*4));
  float* bias1    = (float*)(ws + alloc((size_t)GG*4));
  _Float16* ench  = (_Float16*)(ws + alloc((size_t)FEATD*OBSD*2));
  _Float16* encl  = (_Float16*)(ws + alloc((size_t)FEATD*OBSD*2));
  _Float16* xh    = (_Float16*)(ws + alloc((size_t)TT*BB*DD*2 + 4096));  // x / h2-out hi
  _Float16* xl    = (_Float16*)(ws + alloc((size_t)TT*BB*DD*2 + 4096));  // lo plane
  _Float16* h1h0  = (_Float16*)(ws + alloc((size_t)BB*DD*2));
  _Float16* h1l0  = (_Float16*)(ws + alloc((size_t)BB*DD*2));
  _Float16* h1h1  = (_Float16*)(ws + alloc((size_t)BB*DD*2));
  _Float16* h1l1  = (_Float16*)(ws + alloc((size_t)BB*DD*2));
  int*   flags    = (int*)(ws + alloc((size_t)TT*8*4 + 256));   // + zero page
  _Float16* zp    = (_Float16*)((char*)flags + TT*8*4);

  hipMemsetAsync(flags, 0, (size_t)TT*8*4 + 256, stream);

  k_prep_wsw<<<4096, 256, 0, stream>>>(w_ih0, w_hh0, b_ih0, b_hh0, Wsw0, bias0);
  k_prep_wsw<<<4096, 256, 0, stream>>>(w_ih1, w_hh1, b_ih1, b_hh1, Wsw1, bias1);
  k_conv_encw<<<2048, 256, 0, stream>>>(enc_w, ench, encl);
  k_fill_extra<<<TT*BB/256, 256, 0, stream>>>(reward, last_act, xh, xl);

  dim3 eg(TT*BB/128, FEATD/128);
  k_encoder<<<eg, 256, 0, stream>>>(obs, ench, encl, enc_b, xh, xl);

  k_recur<<<264, 256, 0, stream>>>(xh, xl, h1h0, h1l0, h1h1, h1l1,
                                   Wsw0, Wsw1, bias0, bias1,
                                   terminated, flags, zp);

  k_heads<<<TT*BB/128, 256, 0, stream>>>(xh, xl, pol_w, base_w, pol_b, base_b, (float*)d_out);
}